// Round 9
// baseline (518.722 us; speedup 1.0000x reference)
//
#include <hip/hip_runtime.h>
#include <hip/hip_bf16.h>
#include <math.h>

#define NN 4096
#define EE 65536
#define HH 128
#define EDD 64
#define THD 512

typedef __bf16 bf16;
typedef __bf16 bf16x8 __attribute__((ext_vector_type(8)));
typedef __bf16 bf16x4 __attribute__((ext_vector_type(4)));
typedef float  floatx4 __attribute__((ext_vector_type(4)));

// ---------------------------------------------------------------------------
// Fused setup detect: block 0 = float-dtype detect, block 1 = idx detect,
// blocks 2..17 = zero counts[4096]. One launch replaces 3.
// ---------------------------------------------------------------------------
__global__ __launch_bounds__(256) void k_det0(const void* __restrict__ eaIn,
                                              const int* __restrict__ eidx,
                                              int* __restrict__ dflag,
                                              int* __restrict__ iflag,
                                              int* __restrict__ counts)
{
    int b = blockIdx.x, t = threadIdx.x;
    if (b == 0) {
        if (t < 64) {
            const bf16* p = (const bf16*)eaIn;
            int bad = 0;
            for (int i = 0; i < 32; i++) {
                float v = (float)p[t * 32 + i];
                if (!(v == v) || fabsf(v) > 100.f) bad = 1;
            }
            unsigned long long m = __ballot(bad);
            if (t == 0) *dflag = (m == 0ULL) ? 1 : 0;
        }
    } else if (b == 1) {
        if (t < 64) {
            int bad = 0;
            for (int i = 0; i < 8; i++) {
                int k = t * 8 + i;
                int lo = eidx[2 * k], hi = eidx[2 * k + 1];
                if (hi != 0 || lo < 0 || lo >= NN) bad = 1;
            }
            unsigned long long m = __ballot(bad);
            if (t == 0) *iflag = (m == 0ULL) ? 1 : 0;
        }
    } else {
        counts[(b - 2) * 256 + t] = 0;
    }
}

// extidx + degree count fused
__global__ void k_extcnt(const int* __restrict__ p, int* __restrict__ srcW,
                         int* __restrict__ dstW, const int* __restrict__ iflag,
                         int* __restrict__ counts)
{
    int e = blockIdx.x * 256 + threadIdx.x;
    int s, d;
    if (*iflag) { s = p[2 * e];  d = p[2 * EE + 2 * e]; }
    else        { s = p[e];      d = p[EE + e]; }
    s = min(max(s, 0), NN - 1);
    d = min(max(d, 0), NN - 1);
    srcW[e] = s;
    dstW[e] = d;
    atomicAdd(&counts[d], 1);
}

// ---------------------------------------------------------------------------
// Mega-canonicalize: all dtype-canon jobs in ONE launch.
// modes: 0 = f32 out, 1 = bf16 out, 2 = both, 3 = ea CSR scatter (bf16)
// ---------------------------------------------------------------------------
#define NJOBS 22
struct Job { const void* src; void* dst1; void* dst2; int n; int mode; int blk0; };
struct JobTab { Job j[NJOBS]; };

__global__ __launch_bounds__(256) void k_canon_all(JobTab tab, const int* __restrict__ flag,
                                                   const int* __restrict__ pos)
{
    int b = blockIdx.x;
    int jj = 0;
#pragma unroll
    for (int t = 1; t < NJOBS; t++) if (b >= tab.j[t].blk0) jj = t;
    const Job J = tab.j[jj];
    int i = (b - J.blk0) * 256 + threadIdx.x;
    if (i >= J.n) return;
    float v = (*flag) ? (float)((const bf16*)J.src)[i] : ((const float*)J.src)[i];
    if (J.mode == 0) {
        ((float*)J.dst1)[i] = v;
    } else if (J.mode == 1) {
        ((bf16*)J.dst1)[i] = (bf16)v;
    } else if (J.mode == 2) {
        ((float*)J.dst1)[i] = v;
        ((bf16*)J.dst2)[i] = (bf16)v;
    } else {
        int e = i >> 6, d = i & 63;
        ((bf16*)J.dst1)[(size_t)pos[e] * 64 + d] = (bf16)v;
    }
}

// ---------------------------------------------------------------------------
// Fused post-canon setup: weight repacks (rep_node 1536 | rep_em1 256 |
// ext_em1b 2) + ALL-LAYER wcomb (384 blocks, 4 tf each). One launch.
// ---------------------------------------------------------------------------
__global__ __launch_bounds__(256) void k_setup2(
    const bf16* __restrict__ preWbf, const bf16* __restrict__ em1Wbf,
    const float* __restrict__ em1b,
    bf16* __restrict__ Wnode, bf16* __restrict__ Wem1, float* __restrict__ ext,
    const float* __restrict__ preWc, const float* __restrict__ encWc,
    const float* __restrict__ encbc, const float* __restrict__ prebc,
    bf16* __restrict__ wcombAll, float* __restrict__ bcombAll)
{
    __shared__ float pw[4][128];
    __shared__ float red[4][64];
    int b = blockIdx.x, tid = threadIdx.x;
    if (b < 1536) {                          // rep_node: 3*1024*128 elements
        int i = b * 256 + tid;
        int l = i >> 17, rem = i & 131071;
        int r = rem >> 7, c = rem & 127;
        bf16 v = (r < 512) ? preWbf[(size_t)l * 196608 + (size_t)r * 384 + c]
                           : preWbf[(size_t)l * 196608 + (size_t)(r - 512) * 384 + 128 + c];
        Wnode[i] = v;
    } else if (b < 1792) {                   // rep_em1: 512*128
        int i = (b - 1536) * 256 + tid;
        int r = i >> 7, c = i & 127;
        Wem1[i] = (r < 256) ? em1Wbf[(size_t)r * 256 + c]
                            : em1Wbf[(size_t)(r - 256) * 256 + 128 + c];
    } else if (b < 1794) {                   // ext_em1b: 512
        int i = (b - 1792) * 256 + tid;
        if (i < 512) ext[i] = (i < 256) ? em1b[i] : 0.f;
    } else {                                 // wcomb: 384 blocks x 4 tf
        int q = b - 1794;
        int sub = tid >> 6, d = tid & 63;
        int tf = q * 4 + sub;                // 0..1535
        int l = tf >> 9, tfl = tf & 511;
        const float* pr = preWc + (size_t)l * 196608 + (size_t)tfl * 384 + 256;
        pw[sub][d]      = pr[d];
        pw[sub][d + 64] = pr[d + 64];
        __syncthreads();
        const float* encW = encWc + (size_t)l * 8192;
        float acc = 0.f;
        for (int h = 0; h < 128; h++) acc += pw[sub][h] * encW[h * 64 + d];
        wcombAll[(size_t)l * 32768 + (size_t)tfl * 64 + d] = (bf16)acc;
        float bb = pw[sub][d] * encbc[l * 128 + d] + pw[sub][d + 64] * encbc[l * 128 + 64 + d];
        red[sub][d] = bb;
        __syncthreads();
        for (int s = 32; s > 0; s >>= 1) { if (d < s) red[sub][d] += red[sub][d + s]; __syncthreads(); }
        if (d == 0) {
            bcombAll[l * 1024 + tfl] = red[sub][0] + prebc[l * 512 + tfl];
            bcombAll[l * 1024 + 512 + tfl] = 0.f;
        }
    }
}

// ---------------------------------------------------------------------------
// MFMA bf16 GEMM (validated): C[M,Nout] = act(A @ W^T + bias)
// ---------------------------------------------------------------------------
template<bool RELU, int OM>
__global__ __launch_bounds__(256) void k_mgemm(
    const bf16* __restrict__ A, int lda,
    const bf16* __restrict__ W, int ldw, const float* __restrict__ bias,
    void* __restrict__ Cv, int ldc, int K)
{
    __shared__ bf16 As[64][40];
    __shared__ bf16 Ws[64][40];
    const int m0 = blockIdx.x * 64, n0 = blockIdx.y * 64;
    const int tid = threadIdx.x, wave = tid >> 6, lane = tid & 63;
    const int wm = (wave & 1) * 32, wn = (wave >> 1) * 32;
    const int lrow = tid >> 2, lcol = (tid & 3) * 8;
    const int fr = lane & 15, fk = (lane >> 4) * 8;
    floatx4 acc00 = {0,0,0,0}, acc01 = {0,0,0,0}, acc10 = {0,0,0,0}, acc11 = {0,0,0,0};

    for (int k0 = 0; k0 < K; k0 += 32) {
        bf16x8 av = *(const bf16x8*)(A + (size_t)(m0 + lrow) * lda + k0 + lcol);
        bf16x8 wv = *(const bf16x8*)(W + (size_t)(n0 + lrow) * ldw + k0 + lcol);
        __syncthreads();
        *(bf16x8*)&As[lrow][lcol] = av;
        *(bf16x8*)&Ws[lrow][lcol] = wv;
        __syncthreads();
        bf16x8 a0 = *(const bf16x8*)&As[wm + fr][fk];
        bf16x8 a1 = *(const bf16x8*)&As[wm + 16 + fr][fk];
        bf16x8 b0 = *(const bf16x8*)&Ws[wn + fr][fk];
        bf16x8 b1 = *(const bf16x8*)&Ws[wn + 16 + fr][fk];
        acc00 = __builtin_amdgcn_mfma_f32_16x16x32_bf16(a0, b0, acc00, 0, 0, 0);
        acc01 = __builtin_amdgcn_mfma_f32_16x16x32_bf16(a0, b1, acc01, 0, 0, 0);
        acc10 = __builtin_amdgcn_mfma_f32_16x16x32_bf16(a1, b0, acc10, 0, 0, 0);
        acc11 = __builtin_amdgcn_mfma_f32_16x16x32_bf16(a1, b1, acc11, 0, 0, 0);
    }
    const int cc = lane & 15, cr = (lane >> 4) * 4;
    float vb0 = bias ? bias[n0 + wn + cc] : 0.f;
    float vb1 = bias ? bias[n0 + wn + 16 + cc] : 0.f;
    floatx4 accs[2][2] = {{acc00, acc01}, {acc10, acc11}};
#pragma unroll
    for (int mt = 0; mt < 2; mt++)
#pragma unroll
        for (int nt = 0; nt < 2; nt++) {
            float vb = nt ? vb1 : vb0;
#pragma unroll
            for (int i = 0; i < 4; i++) {
                int gm = m0 + wm + mt * 16 + cr + i;
                int gn = n0 + wn + nt * 16 + cc;
                float v = accs[mt][nt][i] + vb;
                if (RELU) v = fmaxf(v, 0.f);
                if (OM == 1) ((bf16*)Cv)[(size_t)gm * ldc + gn] = (bf16)v;
                else         ((float*)Cv)[(size_t)gm * ldc + gn] = v;
            }
        }
}

// ---------------------------------------------------------------------------
// PNA front: pdps (1024 blks) + qgemm (2048 blks) + gh GEMM (384 blks) in ONE
// launch — all three depend only on out_bf / eaord (available at layer start).
// ---------------------------------------------------------------------------
__global__ __launch_bounds__(256) void k_pna_front(
    const bf16* __restrict__ out_bf, const bf16* __restrict__ Wnode_l,
    const float* __restrict__ bcombx_l, float* __restrict__ Pd, bf16* __restrict__ Ps,
    const bf16* __restrict__ eaord, const bf16* __restrict__ wcomb_l,
    bf16* __restrict__ Qord,
    const bf16* __restrict__ Whh, const float* __restrict__ bhh,
    float* __restrict__ gh)
{
    __shared__ char smem[46080];
    const int b = blockIdx.x;
    const int tid = threadIdx.x, wave = tid >> 6, lane = tid & 63;
    const int fr = lane & 15, fk = (lane >> 4) * 8;
    const int cc = lane & 15, cr = (lane >> 4) * 4;

    if (b < 1024 || b >= 3072) {
        // ---- 64x64 GEMM (pdps or gh), K=128 ----
        bf16 (*As)[40] = (bf16 (*)[40])smem;
        bf16 (*Ws)[40] = (bf16 (*)[40])(smem + 5120);
        const bool isGh = (b >= 3072);
        int m0, n0;
        const bf16* W;
        const float* bias;
        bool isPd = false;
        if (isGh) {
            int g = b - 3072;
            m0 = (g & 63) * 64; n0 = (g >> 6) * 64;
            W = Whh; bias = bhh;
        } else {
            m0 = (b & 63) * 64;
            int y = b >> 6;
            isPd = y < 8;
            n0 = (isPd ? y : y - 8) * 64;
            W = Wnode_l + (isPd ? 0 : (size_t)512 * 128);
            bias = bcombx_l;
        }
        const int wm = (wave & 1) * 32, wn = (wave >> 1) * 32;
        const int lrow = tid >> 2, lcol = (tid & 3) * 8;
        floatx4 acc00 = {0,0,0,0}, acc01 = {0,0,0,0}, acc10 = {0,0,0,0}, acc11 = {0,0,0,0};
        for (int k0 = 0; k0 < 128; k0 += 32) {
            bf16x8 av = *(const bf16x8*)(out_bf + (size_t)(m0 + lrow) * 128 + k0 + lcol);
            bf16x8 wv = *(const bf16x8*)(W + (size_t)(n0 + lrow) * 128 + k0 + lcol);
            __syncthreads();
            *(bf16x8*)&As[lrow][lcol] = av;
            *(bf16x8*)&Ws[lrow][lcol] = wv;
            __syncthreads();
            bf16x8 a0 = *(const bf16x8*)&As[wm + fr][fk];
            bf16x8 a1 = *(const bf16x8*)&As[wm + 16 + fr][fk];
            bf16x8 b0 = *(const bf16x8*)&Ws[wn + fr][fk];
            bf16x8 b1 = *(const bf16x8*)&Ws[wn + 16 + fr][fk];
            acc00 = __builtin_amdgcn_mfma_f32_16x16x32_bf16(a0, b0, acc00, 0, 0, 0);
            acc01 = __builtin_amdgcn_mfma_f32_16x16x32_bf16(a0, b1, acc01, 0, 0, 0);
            acc10 = __builtin_amdgcn_mfma_f32_16x16x32_bf16(a1, b0, acc10, 0, 0, 0);
            acc11 = __builtin_amdgcn_mfma_f32_16x16x32_bf16(a1, b1, acc11, 0, 0, 0);
        }
        float vb0 = (isGh || isPd) ? bias[n0 + wn + cc] : 0.f;
        float vb1 = (isGh || isPd) ? bias[n0 + wn + 16 + cc] : 0.f;
        floatx4 accs[2][2] = {{acc00, acc01}, {acc10, acc11}};
#pragma unroll
        for (int mt = 0; mt < 2; mt++)
#pragma unroll
            for (int nt = 0; nt < 2; nt++) {
                float vb = nt ? vb1 : vb0;
#pragma unroll
                for (int i = 0; i < 4; i++) {
                    int gm = m0 + wm + mt * 16 + cr + i;
                    int gn = n0 + wn + nt * 16 + cc;
                    float v = accs[mt][nt][i] + vb;
                    if (isGh)      gh[(size_t)gm * 384 + gn] = v;
                    else if (isPd) Pd[(size_t)gm * 512 + gn] = v;
                    else           Ps[(size_t)gm * 512 + gn] = (bf16)v;
                }
            }
    } else {
        // ---- qgemm: Q_ord[E,512] = eaord[E,64] @ wcomb[512,64]^T ----
        bf16 (*As)[72] = (bf16 (*)[72])smem;               // 64x72x2 = 9216
        bf16 (*Ws)[72] = (bf16 (*)[72])(smem + 9216);      // 256x72x2 = 36864
        int q = b - 1024;
        const int e0 = (q & 1023) * 64, n0g = (q >> 10) * 256;
#pragma unroll
        for (int v = 0; v < 2; v++) {
            int lin = v * 2048 + tid * 8;
            int r = lin >> 6, c = lin & 63;
            *(bf16x8*)&As[r][c] = *(const bf16x8*)(eaord + (size_t)(e0 + r) * 64 + c);
        }
#pragma unroll
        for (int v = 0; v < 8; v++) {
            int lin = v * 2048 + tid * 8;
            int r = lin >> 6, c = lin & 63;
            *(bf16x8*)&Ws[r][c] = *(const bf16x8*)(wcomb_l + (size_t)(n0g + r) * 64 + c);
        }
        __syncthreads();

        floatx4 acc[4][4];
#pragma unroll
        for (int mt = 0; mt < 4; mt++)
#pragma unroll
            for (int nt = 0; nt < 4; nt++) acc[mt][nt] = (floatx4){0,0,0,0};

#pragma unroll
        for (int kk = 0; kk < 64; kk += 32) {
            bf16x8 af[4], bv[4];
#pragma unroll
            for (int mt = 0; mt < 4; mt++) af[mt] = *(const bf16x8*)&As[mt * 16 + fr][kk + fk];
#pragma unroll
            for (int nt = 0; nt < 4; nt++) bv[nt] = *(const bf16x8*)&Ws[wave * 64 + nt * 16 + fr][kk + fk];
#pragma unroll
            for (int mt = 0; mt < 4; mt++)
#pragma unroll
                for (int nt = 0; nt < 4; nt++)
                    acc[mt][nt] = __builtin_amdgcn_mfma_f32_16x16x32_bf16(af[mt], bv[nt], acc[mt][nt], 0, 0, 0);
        }
#pragma unroll
        for (int mt = 0; mt < 4; mt++)
#pragma unroll
            for (int nt = 0; nt < 4; nt++)
#pragma unroll
                for (int i = 0; i < 4; i++) {
                    int row = mt * 16 + cr + i;
                    int col = n0g + wave * 64 + nt * 16 + cc;
                    Qord[(size_t)(e0 + row) * 512 + col] = (bf16)acc[mt][nt][i];
                }
    }
}

// ---------------------------------------------------------------------------
// gi GEMM: gi = m_bf @ Wih^T + bih. grid (64,6), ldc 384, f32 out.
// ---------------------------------------------------------------------------
__global__ __launch_bounds__(256) void k_gi(
    const bf16* __restrict__ m_bf, const bf16* __restrict__ Wih,
    const float* __restrict__ bih, float* __restrict__ gi)
{
    __shared__ bf16 As[64][40];
    __shared__ bf16 Ws[64][40];
    const int m0 = blockIdx.x * 64, n0 = blockIdx.y * 64;
    const int tid = threadIdx.x, wave = tid >> 6, lane = tid & 63;
    const int wm = (wave & 1) * 32, wn = (wave >> 1) * 32;
    const int lrow = tid >> 2, lcol = (tid & 3) * 8;
    const int fr = lane & 15, fk = (lane >> 4) * 8;
    floatx4 acc00 = {0,0,0,0}, acc01 = {0,0,0,0}, acc10 = {0,0,0,0}, acc11 = {0,0,0,0};

    for (int k0 = 0; k0 < 128; k0 += 32) {
        bf16x8 av = *(const bf16x8*)(m_bf + (size_t)(m0 + lrow) * 128 + k0 + lcol);
        bf16x8 wv = *(const bf16x8*)(Wih + (size_t)(n0 + lrow) * 128 + k0 + lcol);
        __syncthreads();
        *(bf16x8*)&As[lrow][lcol] = av;
        *(bf16x8*)&Ws[lrow][lcol] = wv;
        __syncthreads();
        bf16x8 a0 = *(const bf16x8*)&As[wm + fr][fk];
        bf16x8 a1 = *(const bf16x8*)&As[wm + 16 + fr][fk];
        bf16x8 b0 = *(const bf16x8*)&Ws[wn + fr][fk];
        bf16x8 b1 = *(const bf16x8*)&Ws[wn + 16 + fr][fk];
        acc00 = __builtin_amdgcn_mfma_f32_16x16x32_bf16(a0, b0, acc00, 0, 0, 0);
        acc01 = __builtin_amdgcn_mfma_f32_16x16x32_bf16(a0, b1, acc01, 0, 0, 0);
        acc10 = __builtin_amdgcn_mfma_f32_16x16x32_bf16(a1, b0, acc10, 0, 0, 0);
        acc11 = __builtin_amdgcn_mfma_f32_16x16x32_bf16(a1, b1, acc11, 0, 0, 0);
    }
    const int cc = lane & 15, cr = (lane >> 4) * 4;
    float vb0 = bih[n0 + wn + cc];
    float vb1 = bih[n0 + wn + 16 + cc];
    floatx4 accs[2][2] = {{acc00, acc01}, {acc10, acc11}};
#pragma unroll
    for (int mt = 0; mt < 2; mt++)
#pragma unroll
        for (int nt = 0; nt < 2; nt++) {
            float vb = nt ? vb1 : vb0;
#pragma unroll
            for (int i = 0; i < 4; i++) {
                int gm = m0 + wm + mt * 16 + cr + i;
                int gn = n0 + wn + nt * 16 + cc;
                gi[(size_t)gm * 384 + gn] = accs[mt][nt][i] + vb;
            }
        }
}

// ---------------------------------------------------------------------------
// Fused edge update — NEW: zero LDS staging of MFMA operands. Each lane loads
// its OWN A/B fragments directly from global (bit-identical values to the
// staged path), T14 register prefetch one k-step ahead. SAB (4.2 MB) and the
// three weight matrices (128 KB) are L2/L1-resident, so the 2x fragment
// duplication across waves is ~free. Cross-wave intermediates (med, t2s) stay
// in LDS but are written once per stage → TWO barriers per block (was ~38).
// LDS 43008 B → 3 blocks/CU.
// ---------------------------------------------------------------------------
__global__ __launch_bounds__(256) void k_edge(
    const bf16* __restrict__ SAB,
    const bf16* __restrict__ em2W, const float* __restrict__ em2b,
    const bf16* __restrict__ eu1W, const float* __restrict__ eu1b,
    const bf16* __restrict__ eu2W, const float* __restrict__ eu2b,
    const int* __restrict__ src, const int* __restrict__ dst,
    const int* __restrict__ pos,
    bf16* __restrict__ eaord, float* __restrict__ ea_out_f)
{
    __shared__ char smem[43008];
    bf16 (*med)[200] = (bf16 (*)[200])smem;              // 64x200 = 25600 B
    bf16 (*t2s)[136] = (bf16 (*)[136])(smem + 25600);    // 64x136 = 17408 B

    const int e0 = blockIdx.x * 64;
    const int tid = threadIdx.x, wave = tid >> 6, lane = tid & 63;
    const int fr = lane & 15, fk = (lane >> 4) * 8;
    const int cc = lane & 15, cr = (lane >> 4) * 4;
    const floatx4 z4 = {0.f, 0.f, 0.f, 0.f};
    const int wm1 = (wave & 1) * 32, wn1 = (wave >> 1) * 64;
    const int wm3 = (wave & 1) * 32, wn3 = (wave >> 1) * 32;

    // early gather: ea append tile (held in regs; written to med before barrier)
    const int ar = tid >> 2, ac0 = (tid & 3) * 16;
    const int apr = pos[e0 + ar];
    bf16x8 ea0 = *(const bf16x8*)(eaord + (size_t)apr * 64 + ac0);
    bf16x8 ea1 = *(const bf16x8*)(eaord + (size_t)apr * 64 + ac0 + 8);

    // per-lane A-fragment rows for stage 1
    const int r0 = wm1 + fr, r1 = wm1 + 16 + fr;
    const int s0I = src[e0 + r0], d0I = dst[e0 + r0];
    const int s1I = src[e0 + r1], d1I = dst[e0 + r1];

    // ---------- stage 1: m_ed = relu(A @ em2W^T + em2b)  [64x128, K=256] ----------
    floatx4 acc1[2][4];
#pragma unroll
    for (int mt = 0; mt < 2; mt++)
#pragma unroll
        for (int nt = 0; nt < 4; nt++) acc1[mt][nt] = z4;

    // prologue prefetch (k0 = 0): A raw + B fragments
    bf16x8 as0 = *(const bf16x8*)(SAB + (size_t)s0I * 512 + fk);
    bf16x8 ad0 = *(const bf16x8*)(SAB + (size_t)d0I * 512 + 256 + fk);
    bf16x8 as1 = *(const bf16x8*)(SAB + (size_t)s1I * 512 + fk);
    bf16x8 ad1 = *(const bf16x8*)(SAB + (size_t)d1I * 512 + 256 + fk);
    bf16x8 bw0 = *(const bf16x8*)(em2W + (size_t)(wn1 +      fr) * 256 + fk);
    bf16x8 bw1 = *(const bf16x8*)(em2W + (size_t)(wn1 + 16 + fr) * 256 + fk);
    bf16x8 bw2 = *(const bf16x8*)(em2W + (size_t)(wn1 + 32 + fr) * 256 + fk);
    bf16x8 bw3 = *(const bf16x8*)(em2W + (size_t)(wn1 + 48 + fr) * 256 + fk);

    for (int k0 = 0; k0 < 256; k0 += 32) {
        // convert current A fragments
        bf16 a0[8], a1[8];
#pragma unroll
        for (int j = 0; j < 8; j++) {
            a0[j] = (bf16)fmaxf((float)as0[j] + (float)ad0[j], 0.f);
            a1[j] = (bf16)fmaxf((float)as1[j] + (float)ad1[j], 0.f);
        }
        bf16x8 b0 = bw0, b1 = bw1, b2 = bw2, b3 = bw3;
        int kn = k0 + 32;
        if (kn < 256) {
            as0 = *(const bf16x8*)(SAB + (size_t)s0I * 512 + kn + fk);
            ad0 = *(const bf16x8*)(SAB + (size_t)d0I * 512 + 256 + kn + fk);
            as1 = *(const bf16x8*)(SAB + (size_t)s1I * 512 + kn + fk);
            ad1 = *(const bf16x8*)(SAB + (size_t)d1I * 512 + 256 + kn + fk);
            bw0 = *(const bf16x8*)(em2W + (size_t)(wn1 +      fr) * 256 + kn + fk);
            bw1 = *(const bf16x8*)(em2W + (size_t)(wn1 + 16 + fr) * 256 + kn + fk);
            bw2 = *(const bf16x8*)(em2W + (size_t)(wn1 + 32 + fr) * 256 + kn + fk);
            bw3 = *(const bf16x8*)(em2W + (size_t)(wn1 + 48 + fr) * 256 + kn + fk);
        } else {
            // cross-stage prefetch: stage-2's first B fragments
            bw0 = *(const bf16x8*)(eu1W + (size_t)(wn1 +      fr) * 192 + fk);
            bw1 = *(const bf16x8*)(eu1W + (size_t)(wn1 + 16 + fr) * 192 + fk);
            bw2 = *(const bf16x8*)(eu1W + (size_t)(wn1 + 32 + fr) * 192 + fk);
            bw3 = *(const bf16x8*)(eu1W + (size_t)(wn1 + 48 + fr) * 192 + fk);
        }
        bf16x8 av0 = *(bf16x8*)a0, av1 = *(bf16x8*)a1;
        acc1[0][0] = __builtin_amdgcn_mfma_f32_16x16x32_bf16(av0, b0, acc1[0][0], 0, 0, 0);
        acc1[0][1] = __builtin_amdgcn_mfma_f32_16x16x32_bf16(av0, b1, acc1[0][1], 0, 0, 0);
        acc1[0][2] = __builtin_amdgcn_mfma_f32_16x16x32_bf16(av0, b2, acc1[0][2], 0, 0, 0);
        acc1[0][3] = __builtin_amdgcn_mfma_f32_16x16x32_bf16(av0, b3, acc1[0][3], 0, 0, 0);
        acc1[1][0] = __builtin_amdgcn_mfma_f32_16x16x32_bf16(av1, b0, acc1[1][0], 0, 0, 0);
        acc1[1][1] = __builtin_amdgcn_mfma_f32_16x16x32_bf16(av1, b1, acc1[1][1], 0, 0, 0);
        acc1[1][2] = __builtin_amdgcn_mfma_f32_16x16x32_bf16(av1, b2, acc1[1][2], 0, 0, 0);
        acc1[1][3] = __builtin_amdgcn_mfma_f32_16x16x32_bf16(av1, b3, acc1[1][3], 0, 0, 0);
    }
    // epilogue 1: write m_ed tile + ea append, ONE barrier
#pragma unroll
    for (int mt = 0; mt < 2; mt++)
#pragma unroll
        for (int nt = 0; nt < 4; nt++)
#pragma unroll
            for (int i = 0; i < 4; i++) {
                int row = wm1 + mt * 16 + cr + i;
                int col = wn1 + nt * 16 + cc;
                med[row][col] = (bf16)fmaxf(acc1[mt][nt][i] + em2b[col], 0.f);
            }
    *(bf16x8*)&med[ar][128 + ac0]     = ea0;
    *(bf16x8*)&med[ar][128 + ac0 + 8] = ea1;
    __syncthreads();

    // ---------- stage 2: t2 = relu([m_ed|ea] @ eu1W^T + eu1b)  [64x128, K=192] ----------
    floatx4 acc2[2][4];
#pragma unroll
    for (int mt = 0; mt < 2; mt++)
#pragma unroll
        for (int nt = 0; nt < 4; nt++) acc2[mt][nt] = z4;

    for (int k0 = 0; k0 < 192; k0 += 32) {
        bf16x8 af0 = *(const bf16x8*)&med[wm1 +      fr][k0 + fk];
        bf16x8 af1 = *(const bf16x8*)&med[wm1 + 16 + fr][k0 + fk];
        bf16x8 b0 = bw0, b1 = bw1, b2 = bw2, b3 = bw3;
        int kn = k0 + 32;
        if (kn < 192) {
            bw0 = *(const bf16x8*)(eu1W + (size_t)(wn1 +      fr) * 192 + kn + fk);
            bw1 = *(const bf16x8*)(eu1W + (size_t)(wn1 + 16 + fr) * 192 + kn + fk);
            bw2 = *(const bf16x8*)(eu1W + (size_t)(wn1 + 32 + fr) * 192 + kn + fk);
            bw3 = *(const bf16x8*)(eu1W + (size_t)(wn1 + 48 + fr) * 192 + kn + fk);
        } else {
            // cross-stage prefetch: stage-3's first B fragments (only 2 needed)
            bw0 = *(const bf16x8*)(eu2W + (size_t)(wn3 +      fr) * 128 + fk);
            bw1 = *(const bf16x8*)(eu2W + (size_t)(wn3 + 16 + fr) * 128 + fk);
        }
        acc2[0][0] = __builtin_amdgcn_mfma_f32_16x16x32_bf16(af0, b0, acc2[0][0], 0, 0, 0);
        acc2[0][1] = __builtin_amdgcn_mfma_f32_16x16x32_bf16(af0, b1, acc2[0][1], 0, 0, 0);
        acc2[0][2] = __builtin_amdgcn_mfma_f32_16x16x32_bf16(af0, b2, acc2[0][2], 0, 0, 0);
        acc2[0][3] = __builtin_amdgcn_mfma_f32_16x16x32_bf16(af0, b3, acc2[0][3], 0, 0, 0);
        acc2[1][0] = __builtin_amdgcn_mfma_f32_16x16x32_bf16(af1, b0, acc2[1][0], 0, 0, 0);
        acc2[1][1] = __builtin_amdgcn_mfma_f32_16x16x32_bf16(af1, b1, acc2[1][1], 0, 0, 0);
        acc2[1][2] = __builtin_amdgcn_mfma_f32_16x16x32_bf16(af1, b2, acc2[1][2], 0, 0, 0);
        acc2[1][3] = __builtin_amdgcn_mfma_f32_16x16x32_bf16(af1, b3, acc2[1][3], 0, 0, 0);
    }
    // epilogue 2: write t2 tile, ONE barrier
#pragma unroll
    for (int mt = 0; mt < 2; mt++)
#pragma unroll
        for (int nt = 0; nt < 4; nt++)
#pragma unroll
            for (int i = 0; i < 4; i++) {
                int row = wm1 + mt * 16 + cr + i;
                int col = wn1 + nt * 16 + cc;
                t2s[row][col] = (bf16)fmaxf(acc2[mt][nt][i] + eu1b[col], 0.f);
            }
    __syncthreads();

    // ---------- stage 3: ea' = t2 @ eu2W^T + eu2b  [64x64, K=128] ----------
    floatx4 acc3[2][2];
#pragma unroll
    for (int mt = 0; mt < 2; mt++)
#pragma unroll
        for (int nt = 0; nt < 2; nt++) acc3[mt][nt] = z4;

    for (int k0 = 0; k0 < 128; k0 += 32) {
        bf16x8 af0 = *(const bf16x8*)&t2s[wm3 +      fr][k0 + fk];
        bf16x8 af1 = *(const bf16x8*)&t2s[wm3 + 16 + fr][k0 + fk];
        bf16x8 b0 = bw0, b1 = bw1;
        int kn = k0 + 32;
        if (kn < 128) {
            bw0 = *(const bf16x8*)(eu2W + (size_t)(wn3 +      fr) * 128 + kn + fk);
            bw1 = *(const bf16x8*)(eu2W + (size_t)(wn3 + 16 + fr) * 128 + kn + fk);
        }
        acc3[0][0] = __builtin_amdgcn_mfma_f32_16x16x32_bf16(af0, b0, acc3[0][0], 0, 0, 0);
        acc3[0][1] = __builtin_amdgcn_mfma_f32_16x16x32_bf16(af0, b1, acc3[0][1], 0, 0, 0);
        acc3[1][0] = __builtin_amdgcn_mfma_f32_16x16x32_bf16(af1, b0, acc3[1][0], 0, 0, 0);
        acc3[1][1] = __builtin_amdgcn_mfma_f32_16x16x32_bf16(af1, b1, acc3[1][1], 0, 0, 0);
    }
#pragma unroll
    for (int mt = 0; mt < 2; mt++)
#pragma unroll
        for (int nt = 0; nt < 2; nt++)
#pragma unroll
            for (int i = 0; i < 4; i++) {
                int row = wm3 + mt * 16 + cr + i;
                int col = wn3 + nt * 16 + cc;
                float v = acc3[mt][nt][i] + eu2b[col];
                int e = e0 + row;
                eaord[(size_t)pos[e] * 64 + col] = (bf16)v;
                if (ea_out_f) ea_out_f[(size_t)e * 64 + col] = v;  // final layer only
            }
}

// ---------------------------------------------------------------------------
// Post-MLP per-tower MFMA GEMM — consumes bf16 agg buffers
// ---------------------------------------------------------------------------
__global__ __launch_bounds__(256) void k_postg(
    const bf16* __restrict__ xin, const bf16* __restrict__ aggX,
    const bf16* __restrict__ aggS, const bf16* __restrict__ aggM,
    const bf16* __restrict__ qWbf, const float* __restrict__ qb,
    bf16* __restrict__ ybf)
{
    __shared__ bf16 As[64][40];
    __shared__ bf16 Ws[32][40];
    const int n0 = blockIdx.x * 64, t = blockIdx.y;
    const int tid = threadIdx.x, wave = tid >> 6, lane = tid & 63;
    const int lrow = tid >> 2, lcol = (tid & 3) * 8;
    const int fr = lane & 15, fk = (lane >> 4) * 8;
    floatx4 acc0 = {0,0,0,0}, acc1 = {0,0,0,0};

    for (int k0 = 0; k0 < 512; k0 += 32) {
        int n = n0 + lrow;
        int c0 = k0 + lcol;
        const bf16* srcp;
        if (c0 < 128)      srcp = xin  + (size_t)n * 128 + c0;
        else if (c0 < 256) srcp = aggX + (size_t)n * 512 + t * 128 + (c0 - 128);
        else if (c0 < 384) srcp = aggS + (size_t)n * 512 + t * 128 + (c0 - 256);
        else               srcp = aggM + (size_t)n * 512 + t * 128 + (c0 - 384);
        bf16x8 a8 = *(const bf16x8*)srcp;
        bf16 w8[8];
        if (tid < 128) {
            int wr = tid >> 2, wc = (tid & 3) * 8;
            *(bf16x8*)w8 = *(const bf16x8*)(qWbf + (size_t)(t * 32 + wr) * 512 + k0 + wc);
        }
        __syncthreads();
        *(bf16x8*)&As[lrow][lcol] = a8;
        if (tid < 128) {
            int wr = tid >> 2, wc = (tid & 3) * 8;
            *(bf16x8*)&Ws[wr][wc] = *(bf16x8*)w8;
        }
        __syncthreads();
        bf16x8 a  = *(const bf16x8*)&As[wave * 16 + fr][fk];
        bf16x8 b0 = *(const bf16x8*)&Ws[fr][fk];
        bf16x8 b1 = *(const bf16x8*)&Ws[16 + fr][fk];
        acc0 = __builtin_amdgcn_mfma_f32_16x16x32_bf16(a, b0, acc0, 0, 0, 0);
        acc1 = __builtin_amdgcn_mfma_f32_16x16x32_bf16(a, b1, acc1, 0, 0, 0);
    }
    const int cc = lane & 15, cr = (lane >> 4) * 4;
#pragma unroll
    for (int i = 0; i < 4; i++) {
        int gn = n0 + wave * 16 + cr + i;
        ybf[(size_t)gn * 128 + t * 32 + cc]      = (bf16)(acc0[i] + qb[t * 32 + cc]);
        ybf[(size_t)gn * 128 + t * 32 + 16 + cc] = (bf16)(acc1[i] + qb[t * 32 + 16 + cc]);
    }
}

// ----------------------- CSR scan / fill ------------------------------------
__global__ __launch_bounds__(1024) void k_scan(
    const int* __restrict__ counts, int* __restrict__ offs, int* __restrict__ cursor)
{
    __shared__ int ls[1024];
    int tid = threadIdx.x, base = tid * 4;
    int c0 = counts[base], c1 = counts[base + 1], c2 = counts[base + 2], c3 = counts[base + 3];
    ls[tid] = c0 + c1 + c2 + c3;
    __syncthreads();
    for (int d = 1; d < 1024; d <<= 1) {
        int v = (tid >= d) ? ls[tid - d] : 0;
        __syncthreads();
        ls[tid] += v;
        __syncthreads();
    }
    int r = tid ? ls[tid - 1] : 0;
    offs[base] = r;     cursor[base] = r;     r += c0;
    offs[base + 1] = r; cursor[base + 1] = r; r += c1;
    offs[base + 2] = r; cursor[base + 2] = r; r += c2;
    offs[base + 3] = r; cursor[base + 3] = r; r += c3;
    if (tid == 1023) offs[4096] = r;
}

__global__ void k_fill(const int* __restrict__ dst, const int* __restrict__ srcW,
                       int* __restrict__ cursor, int* __restrict__ pos,
                       int* __restrict__ srcord)
{
    int e = blockIdx.x * 256 + threadIdx.x;
    int p = atomicAdd(&cursor[dst[e]], 1);
    pos[e] = p;
    srcord[p] = srcW[e];
}

// ---------------------------------------------------------------------------
// Single-pass aggregation. Pd f32 (own row, sequential); Ps bf16 L2-resident.
// ---------------------------------------------------------------------------
__global__ __launch_bounds__(128) void k_agg(
    const float* __restrict__ Pd, const bf16* __restrict__ Ps,
    const bf16* __restrict__ Qord,
    const int* __restrict__ srcord, const int* __restrict__ offs,
    bf16* __restrict__ aggX, bf16* __restrict__ aggS, bf16* __restrict__ aggM)
{
    int n = blockIdx.x, tid = threadIdx.x;
    int c = tid * 4;
    float4 pd = *(const float4*)(Pd + (size_t)n * 512 + c);
    float s0 = 0, s1 = 0, s2 = 0, s3 = 0;
    float q0 = 0, q1 = 0, q2 = 0, q3 = 0;
    float x0 = -3e38f, x1 = -3e38f, x2 = -3e38f, x3 = -3e38f;
    int beg = offs[n], end = offs[n + 1];
    for (int i = beg; i < end; i++) {
        int sn = srcord[i];
        bf16x4 psv = *(const bf16x4*)(Ps + (size_t)sn * 512 + c);
        bf16x4 qv  = *(const bf16x4*)(Qord + (size_t)i * 512 + c);
        float m0 = pd.x + (float)psv[0] + (float)qv[0];
        float m1 = pd.y + (float)psv[1] + (float)qv[1];
        float m2 = pd.z + (float)psv[2] + (float)qv[2];
        float m3 = pd.w + (float)psv[3] + (float)qv[3];
        s0 += m0; s1 += m1; s2 += m2; s3 += m3;
        q0 += m0 * m0; q1 += m1 * m1; q2 += m2 * m2; q3 += m3 * m3;
        x0 = fmaxf(x0, m0); x1 = fmaxf(x1, m1); x2 = fmaxf(x2, m2); x3 = fmaxf(x3, m3);
    }
    int cnt = end - beg;
    float inv = 1.f / fmaxf((float)cnt, 1.f);
    float me0 = s0 * inv, me1 = s1 * inv, me2 = s2 * inv, me3 = s3 * inv;
    float v0 = fmaxf(q0 * inv - me0 * me0, 0.f);
    float v1 = fmaxf(q1 * inv - me1 * me1, 0.f);
    float v2 = fmaxf(q2 * inv - me2 * me2, 0.f);
    float v3 = fmaxf(q3 * inv - me3 * me3, 0.f);
    size_t o = (size_t)n * 512 + c;
    bf16x4 mx, st, me;
    mx[0] = (bf16)(cnt > 0 ? x0 : 0.f); mx[1] = (bf16)(cnt > 0 ? x1 : 0.f);
    mx[2] = (bf16)(cnt > 0 ? x2 : 0.f); mx[3] = (bf16)(cnt > 0 ? x3 : 0.f);
    st[0] = (bf16)sqrtf(v0 + 1e-5f); st[1] = (bf16)sqrtf(v1 + 1e-5f);
    st[2] = (bf16)sqrtf(v2 + 1e-5f); st[3] = (bf16)sqrtf(v3 + 1e-5f);
    me[0] = (bf16)me0; me[1] = (bf16)me1; me[2] = (bf16)me2; me[3] = (bf16)me3;
    *(bf16x4*)(aggX + o) = mx;
    *(bf16x4*)(aggS + o) = st;
    *(bf16x4*)(aggM + o) = me;
}

// --------------------------- GRU elementwise --------------------------------
__global__ void k_gru(const float* __restrict__ gi, const float* __restrict__ gh,
                      float* __restrict__ hst, bf16* __restrict__ ob,
                      float* __restrict__ fo)
{
    int i = blockIdx.x * 256 + threadIdx.x;
    int k = i & 127;
    size_t b = (size_t)(i >> 7) * 384;
    float ir = gi[b + k],       hr = gh[b + k];
    float iz = gi[b + 128 + k], hz = gh[b + 128 + k];
    float ic = gi[b + 256 + k], hc = gh[b + 256 + k];
    float r = 1.f / (1.f + __expf(-(ir + hr)));
    float z = 1.f / (1.f + __expf(-(iz + hz)));
    float c = tanhf(ic + r * hc);
    float h = hst[i];
    float hn = (1.f - z) * c + z * h;
    hst[i] = hn;
    ob[i] = (bf16)hn;
    if (fo) { fo[i] = hn; fo[4718592 + i] = hn; }
}

__global__ void k_sentinel(float* __restrict__ o, float v)
{
    int i = blockIdx.x * 256 + threadIdx.x;
    o[i] = v;
}

// ===========================================================================
extern "C" void kernel_launch(void* const* d_in, const int* in_sizes, int n_in,
                              void* d_out, int out_size, void* d_ws, size_t ws_size,
                              hipStream_t stream)
{
    static const int exp_sizes[23] = {
        524288, 4194304, 131072, 24576, 384, 589824, 1536, 196608, 384,
        49152, 384, 49152, 49152, 384, 384, 65536, 256, 32768, 128,
        24576, 128, 8192, 64 };
    if (n_in != 23) { k_sentinel<<<2048, 256, 0, stream>>>((float*)d_out, 200.f); return; }
    for (int i = 0; i < 23; i++)
        if (in_sizes[i] != exp_sizes[i]) {
            k_sentinel<<<2048, 256, 0, stream>>>((float*)d_out, 60.f + 4.f * i);
            return;
        }
    if (out_size != 5242880) { k_sentinel<<<2048, 256, 0, stream>>>((float*)d_out, 52.f); return; }

    const int* eidx = (const int*)d_in[2];

    char* w = (char*)d_ws;
    size_t off = 0;
    auto alloc = [&](size_t bytes) -> char* {
        char* p = w + off;
        off = (off + bytes + 255) & ~(size_t)255;
        return p;
    };
    int*   dflag   = (int*)  alloc(256);
    int*   iflag   = (int*)  alloc(256);
    int*   srcW    = (int*)  alloc((size_t)EE * 4);
    int*   dstW    = (int*)  alloc((size_t)EE * 4);
    int*   pos     = (int*)  alloc((size_t)EE * 4);
    int*   srcord  = (int*)  alloc((size_t)EE * 4);
    float* out_f32 = (float*)alloc((size_t)NN * HH * 4);
    bf16*  out_bf  = (bf16*) alloc((size_t)NN * HH * 2);
    bf16*  m_bf    = (bf16*) alloc((size_t)NN * HH * 2);
    bf16*  ybf     = (bf16*) alloc((size_t)NN * HH * 2);
    bf16*  eaord   = (bf16*) alloc((size_t)EE * EDD * 2);
    bf16*  wcombAll= (bf16*) alloc((size_t)3 * THD * EDD * 2);
    float* bcombAll= (float*)alloc((size_t)3 * 1024 * 4);
    int*   counts  = (int*)  alloc((size_t)NN * 4);
    int*   offs    = (int*)  alloc((size_t)(NN + 1) * 4);
    int*   cursor  = (int*)  alloc((size_t)NN * 4);
    float* Pd      = (float*)alloc((size_t)NN * THD * 4);   // [4096,512] f32
    bf16*  Ps      = (bf16*) alloc((size_t)NN * THD * 2);   // [4096,512] bf16 (L2-resident)
    bf16*  aggX    = (bf16*) alloc((size_t)NN * THD * 2);
    bf16*  aggS    = (bf16*) alloc((size_t)NN * THD * 2);
    bf16*  aggM    = (bf16*) alloc((size_t)NN * THD * 2);
    float* giB     = (float*)alloc((size_t)NN * 384 * 4);   // dedicated (gh computed early)
    float* ghB     = (float*)alloc((size_t)NN * 384 * 4);
    float* encWc  = (float*)alloc((size_t)24576 * 4);
    float* encbc  = (float*)alloc((size_t)384 * 4);
    float* preWc  = (float*)alloc((size_t)589824 * 4);
    float* prebc  = (float*)alloc((size_t)1536 * 4);
    float* postbc = (float*)alloc((size_t)384 * 4);
    float* linbc  = (float*)alloc((size_t)384 * 4);
    float* bihc   = (float*)alloc((size_t)384 * 4);
    float* bhhc   = (float*)alloc((size_t)384 * 4);
    float* em1bc  = (float*)alloc((size_t)256 * 4);
    float* em1ext = (float*)alloc((size_t)512 * 4);
    float* em2bc  = (float*)alloc((size_t)128 * 4);
    float* eu1bc  = (float*)alloc((size_t)128 * 4);
    float* eu2bc  = (float*)alloc((size_t)64 * 4);
    bf16* preWbf = (bf16*)alloc((size_t)589824 * 2);
    bf16* WnodeBf= (bf16*)alloc((size_t)3 * 131072 * 2);
    bf16* postWbf= (bf16*)alloc((size_t)196608 * 2);
    bf16* linWbf = (bf16*)alloc((size_t)49152 * 2);
    bf16* WihBf  = (bf16*)alloc((size_t)49152 * 2);
    bf16* WhhBf  = (bf16*)alloc((size_t)49152 * 2);
    bf16* em1Wbf = (bf16*)alloc((size_t)65536 * 2);
    bf16* Wem1Bf = (bf16*)alloc((size_t)65536 * 2);
    bf16* em2Wbf = (bf16*)alloc((size_t)32768 * 2);
    bf16* eu1Wbf = (bf16*)alloc((size_t)24576 * 2);
    bf16* eu2Wbf = (bf16*)alloc((size_t)8192 * 2);
    // phase-shared region: Q_ord (PNA) / SAB (edge, bf16)
    char* region = alloc((size_t)EE * 512 * 2);     // 67.1 MB
    bf16*  Qord = (bf16*) (region);
    bf16*  SAB  = (bf16*) (region);                 // [N,512] bf16 = 4.2 MB

    if (ws_size < off) { k_sentinel<<<2048, 256, 0, stream>>>((float*)d_out, 44.f); return; }

    // ---- setup: detect+zero / extidx+count / scan / fill ----
    k_det0<<<18, 256, 0, stream>>>(d_in[1], eidx, dflag, iflag, counts);
    k_extcnt<<<EE / 256, 256, 0, stream>>>(eidx, srcW, dstW, iflag, counts);
    k_scan<<<1, 1024, 0, stream>>>(counts, offs, cursor);
    k_fill<<<EE / 256, 256, 0, stream>>>(dstW, srcW, cursor, pos, srcord);

    // ---- ONE mega-canon launch ----
    {
        JobTab tab;
        int bi = 0, ji = 0;
        auto add = [&](const void* s, void* d1, void* d2, int n, int mode) {
            tab.j[ji] = { s, d1, d2, n, mode, bi };
            bi += (n + 255) / 256;
            ji++;
        };
        add(d_in[0],  out_f32, out_bf, 524288, 2);
        add(d_in[1],  eaord,   nullptr, 4194304, 3);
        add(d_in[5],  preWc,   preWbf, 589824, 2);
        add(d_in[3],  encWc,   nullptr, 24576, 0);
        add(d_in[4],  encbc,   nullptr, 384, 0);
        add(d_in[6],  prebc,   nullptr, 1536, 0);
        add(d_in[8],  postbc,  nullptr, 384, 0);
        add(d_in[10], linbc,   nullptr, 384, 0);
        add(d_in[13], bihc,    nullptr, 384, 0);
        add(d_in[14], bhhc,    nullptr, 384, 0);
        add(d_in[16], em1bc,   nullptr, 256, 0);
        add(d_in[18], em2bc,   nullptr, 128, 0);
        add(d_in[20], eu1bc,   nullptr, 128, 0);
        add(d_in[22], eu2bc,   nullptr, 64, 0);
        add(d_in[7],  postWbf, nullptr, 196608, 1);
        add(d_in[9],  linWbf,  nullptr, 49152, 1);
        add(d_in[11], WihBf,   nullptr, 49152, 1);
        add(d_in[12], WhhBf,   nullptr, 49152, 1);
        add(d_in[15], em1Wbf,  nullptr, 65536, 1);
        add(d_in[17], em2Wbf,  nullptr, 32768, 1);
        add(d_in[19], eu1Wbf,  nullptr, 24576, 1);
        add(d_in[21], eu2Wbf,  nullptr, 8192, 1);
        k_canon_all<<<bi, 256, 0, stream>>>(tab, dflag, pos);
    }
    // ---- fused repacks + all-layer wcomb ----
    k_setup2<<<2178, 256, 0, stream>>>(preWbf, em1Wbf, em1bc, WnodeBf, Wem1Bf, em1ext,
                                       preWc, encWc, encbc, prebc, wcombAll, bcombAll);

    auto GEMM = [&](const bf16* A, int lda, const bf16* Wm, int ldw, const float* bias,
                    void* C, int ldc, int M, int Nout, int K, bool relu, int om) {
        dim3 grid(M / 64, Nout / 64);
        if (relu) {
            if (om) k_mgemm<true, 1><<<grid, 256, 0, stream>>>(A, lda, Wm, ldw, bias, C, ldc, K);
            else    k_mgemm<true, 0><<<grid, 256, 0, stream>>>(A, lda, Wm, ldw, bias, C, ldc, K);
        } else {
            if (om) k_mgemm<false, 1><<<grid, 256, 0, stream>>>(A, lda, Wm, ldw, bias, C, ldc, K);
            else    k_mgemm<false, 0><<<grid, 256, 0, stream>>>(A, lda, Wm, ldw, bias, C, ldc, K);
        }
    };

    for (int l = 0; l < 3; l++) {
        const bf16*  Wnode_l  = WnodeBf + (size_t)l * 131072;
        const bf16*  postW_l  = postWbf + (size_t)l * 65536;
        const float* postb_l  = postbc + (size_t)l * 128;
        const bf16*  linW_l   = linWbf + (size_t)l * 16384;
        const float* linb_l   = linbc  + (size_t)l * 128;
        const bf16*  wcomb_l  = wcombAll + (size_t)l * 32768;
        const float* bcombx_l = bcombAll + (size_t)l * 1024;
        const bool last = (l == 2);

        // ---- PNA front: pdps + qgemm + gh in one launch ----
        k_pna_front<<<3456, 256, 0, stream>>>(out_bf, Wnode_l, bcombx_l, Pd, Ps,
                                              eaord, wcomb_l, Qord, WhhBf, bhhc, ghB);
        k_agg<<<NN, 128, 0, stream>>>(Pd, Ps, Qord, srcord, offs, aggX, aggS, aggM);
        k_postg<<<dim3(NN / 64, 4), 256, 0, stream>>>(out_bf, aggX, aggS, aggM,
                                                      postW_l, postb_l, ybf);
        GEMM(ybf, HH, linW_l, HH, linb_l, m_bf, HH, NN, HH, HH, true, 1);
        // ---- GRU: gi then elementwise (gh already computed in pna_front) ----
        k_gi<<<dim3(64, 6), 256, 0, stream>>>(m_bf, WihBf, bihc, giB);
        k_gru<<<NN * HH / 256, 256, 0, stream>>>(giB, ghB, out_f32, out_bf,
                                                 last ? (float*)d_out : (float*)nullptr);
        // ---- edge update (merged SAB + fused chain; SAB bf16) ----
        GEMM(out_bf, HH, Wem1Bf, 128, em1ext, SAB, 512, NN, 512, HH, false, 1);
        k_edge<<<EE / 64, 256, 0, stream>>>(SAB, em2Wbf, em2bc, eu1Wbf, eu1bc,
                                            eu2Wbf, eu2bc, srcW, dstW, pos,
                                            eaord, last ? (float*)d_out + 524288 : (float*)nullptr);
    }
}

// Round 10
// 509.733 us; speedup vs baseline: 1.0176x; 1.0176x over previous
//
#include <hip/hip_runtime.h>
#include <hip/hip_bf16.h>
#include <math.h>

#define NN 4096
#define EE 65536
#define HH 128
#define EDD 64
#define THD 512

typedef __bf16 bf16;
typedef __bf16 bf16x8 __attribute__((ext_vector_type(8)));
typedef __bf16 bf16x4 __attribute__((ext_vector_type(4)));
typedef float  floatx4 __attribute__((ext_vector_type(4)));

// ---------------------------------------------------------------------------
// Fused setup detect: block 0 = float-dtype detect, block 1 = idx detect,
// blocks 2..17 = zero counts[4096]. One launch replaces 3.
// ---------------------------------------------------------------------------
__global__ __launch_bounds__(256) void k_det0(const void* __restrict__ eaIn,
                                              const int* __restrict__ eidx,
                                              int* __restrict__ dflag,
                                              int* __restrict__ iflag,
                                              int* __restrict__ counts)
{
    int b = blockIdx.x, t = threadIdx.x;
    if (b == 0) {
        if (t < 64) {
            const bf16* p = (const bf16*)eaIn;
            int bad = 0;
            for (int i = 0; i < 32; i++) {
                float v = (float)p[t * 32 + i];
                if (!(v == v) || fabsf(v) > 100.f) bad = 1;
            }
            unsigned long long m = __ballot(bad);
            if (t == 0) *dflag = (m == 0ULL) ? 1 : 0;
        }
    } else if (b == 1) {
        if (t < 64) {
            int bad = 0;
            for (int i = 0; i < 8; i++) {
                int k = t * 8 + i;
                int lo = eidx[2 * k], hi = eidx[2 * k + 1];
                if (hi != 0 || lo < 0 || lo >= NN) bad = 1;
            }
            unsigned long long m = __ballot(bad);
            if (t == 0) *iflag = (m == 0ULL) ? 1 : 0;
        }
    } else {
        counts[(b - 2) * 256 + t] = 0;
    }
}

// extidx + degree count fused
__global__ void k_extcnt(const int* __restrict__ p, int* __restrict__ srcW,
                         int* __restrict__ dstW, const int* __restrict__ iflag,
                         int* __restrict__ counts)
{
    int e = blockIdx.x * 256 + threadIdx.x;
    int s, d;
    if (*iflag) { s = p[2 * e];  d = p[2 * EE + 2 * e]; }
    else        { s = p[e];      d = p[EE + e]; }
    s = min(max(s, 0), NN - 1);
    d = min(max(d, 0), NN - 1);
    srcW[e] = s;
    dstW[e] = d;
    atomicAdd(&counts[d], 1);
}

// ---------------------------------------------------------------------------
// Mega-canonicalize: all dtype-canon jobs in ONE launch.
// modes: 0 = f32 out, 1 = bf16 out, 2 = both, 3 = ea CSR scatter (bf16)
// ---------------------------------------------------------------------------
#define NJOBS 22
struct Job { const void* src; void* dst1; void* dst2; int n; int mode; int blk0; };
struct JobTab { Job j[NJOBS]; };

__global__ __launch_bounds__(256) void k_canon_all(JobTab tab, const int* __restrict__ flag,
                                                   const int* __restrict__ pos)
{
    int b = blockIdx.x;
    int jj = 0;
#pragma unroll
    for (int t = 1; t < NJOBS; t++) if (b >= tab.j[t].blk0) jj = t;
    const Job J = tab.j[jj];
    int i = (b - J.blk0) * 256 + threadIdx.x;
    if (i >= J.n) return;
    float v = (*flag) ? (float)((const bf16*)J.src)[i] : ((const float*)J.src)[i];
    if (J.mode == 0) {
        ((float*)J.dst1)[i] = v;
    } else if (J.mode == 1) {
        ((bf16*)J.dst1)[i] = (bf16)v;
    } else if (J.mode == 2) {
        ((float*)J.dst1)[i] = v;
        ((bf16*)J.dst2)[i] = (bf16)v;
    } else {
        int e = i >> 6, d = i & 63;
        ((bf16*)J.dst1)[(size_t)pos[e] * 64 + d] = (bf16)v;
    }
}

// ---------------------------------------------------------------------------
// Fused post-canon setup: weight repacks (rep_node 1536 | rep_em1 256 |
// ext_em1b 2) + ALL-LAYER wcomb (384 blocks, 4 tf each). One launch.
// ---------------------------------------------------------------------------
__global__ __launch_bounds__(256) void k_setup2(
    const bf16* __restrict__ preWbf, const bf16* __restrict__ em1Wbf,
    const float* __restrict__ em1b,
    bf16* __restrict__ Wnode, bf16* __restrict__ Wem1, float* __restrict__ ext,
    const float* __restrict__ preWc, const float* __restrict__ encWc,
    const float* __restrict__ encbc, const float* __restrict__ prebc,
    bf16* __restrict__ wcombAll, float* __restrict__ bcombAll)
{
    __shared__ float pw[4][128];
    __shared__ float red[4][64];
    int b = blockIdx.x, tid = threadIdx.x;
    if (b < 1536) {                          // rep_node: 3*1024*128 elements
        int i = b * 256 + tid;
        int l = i >> 17, rem = i & 131071;
        int r = rem >> 7, c = rem & 127;
        bf16 v = (r < 512) ? preWbf[(size_t)l * 196608 + (size_t)r * 384 + c]
                           : preWbf[(size_t)l * 196608 + (size_t)(r - 512) * 384 + 128 + c];
        Wnode[i] = v;
    } else if (b < 1792) {                   // rep_em1: 512*128
        int i = (b - 1536) * 256 + tid;
        int r = i >> 7, c = i & 127;
        Wem1[i] = (r < 256) ? em1Wbf[(size_t)r * 256 + c]
                            : em1Wbf[(size_t)(r - 256) * 256 + 128 + c];
    } else if (b < 1794) {                   // ext_em1b: 512
        int i = (b - 1792) * 256 + tid;
        if (i < 512) ext[i] = (i < 256) ? em1b[i] : 0.f;
    } else {                                 // wcomb: 384 blocks x 4 tf
        int q = b - 1794;
        int sub = tid >> 6, d = tid & 63;
        int tf = q * 4 + sub;                // 0..1535
        int l = tf >> 9, tfl = tf & 511;
        const float* pr = preWc + (size_t)l * 196608 + (size_t)tfl * 384 + 256;
        pw[sub][d]      = pr[d];
        pw[sub][d + 64] = pr[d + 64];
        __syncthreads();
        const float* encW = encWc + (size_t)l * 8192;
        float acc = 0.f;
        for (int h = 0; h < 128; h++) acc += pw[sub][h] * encW[h * 64 + d];
        wcombAll[(size_t)l * 32768 + (size_t)tfl * 64 + d] = (bf16)acc;
        float bb = pw[sub][d] * encbc[l * 128 + d] + pw[sub][d + 64] * encbc[l * 128 + 64 + d];
        red[sub][d] = bb;
        __syncthreads();
        for (int s = 32; s > 0; s >>= 1) { if (d < s) red[sub][d] += red[sub][d + s]; __syncthreads(); }
        if (d == 0) {
            bcombAll[l * 1024 + tfl] = red[sub][0] + prebc[l * 512 + tfl];
            bcombAll[l * 1024 + 512 + tfl] = 0.f;
        }
    }
}

// ---------------------------------------------------------------------------
// MFMA bf16 GEMM (validated): C[M,Nout] = act(A @ W^T + bias)
// ---------------------------------------------------------------------------
template<bool RELU, int OM>
__global__ __launch_bounds__(256) void k_mgemm(
    const bf16* __restrict__ A, int lda,
    const bf16* __restrict__ W, int ldw, const float* __restrict__ bias,
    void* __restrict__ Cv, int ldc, int K)
{
    __shared__ bf16 As[64][40];
    __shared__ bf16 Ws[64][40];
    const int m0 = blockIdx.x * 64, n0 = blockIdx.y * 64;
    const int tid = threadIdx.x, wave = tid >> 6, lane = tid & 63;
    const int wm = (wave & 1) * 32, wn = (wave >> 1) * 32;
    const int lrow = tid >> 2, lcol = (tid & 3) * 8;
    const int fr = lane & 15, fk = (lane >> 4) * 8;
    floatx4 acc00 = {0,0,0,0}, acc01 = {0,0,0,0}, acc10 = {0,0,0,0}, acc11 = {0,0,0,0};

    for (int k0 = 0; k0 < K; k0 += 32) {
        bf16x8 av = *(const bf16x8*)(A + (size_t)(m0 + lrow) * lda + k0 + lcol);
        bf16x8 wv = *(const bf16x8*)(W + (size_t)(n0 + lrow) * ldw + k0 + lcol);
        __syncthreads();
        *(bf16x8*)&As[lrow][lcol] = av;
        *(bf16x8*)&Ws[lrow][lcol] = wv;
        __syncthreads();
        bf16x8 a0 = *(const bf16x8*)&As[wm + fr][fk];
        bf16x8 a1 = *(const bf16x8*)&As[wm + 16 + fr][fk];
        bf16x8 b0 = *(const bf16x8*)&Ws[wn + fr][fk];
        bf16x8 b1 = *(const bf16x8*)&Ws[wn + 16 + fr][fk];
        acc00 = __builtin_amdgcn_mfma_f32_16x16x32_bf16(a0, b0, acc00, 0, 0, 0);
        acc01 = __builtin_amdgcn_mfma_f32_16x16x32_bf16(a0, b1, acc01, 0, 0, 0);
        acc10 = __builtin_amdgcn_mfma_f32_16x16x32_bf16(a1, b0, acc10, 0, 0, 0);
        acc11 = __builtin_amdgcn_mfma_f32_16x16x32_bf16(a1, b1, acc11, 0, 0, 0);
    }
    const int cc = lane & 15, cr = (lane >> 4) * 4;
    float vb0 = bias ? bias[n0 + wn + cc] : 0.f;
    float vb1 = bias ? bias[n0 + wn + 16 + cc] : 0.f;
    floatx4 accs[2][2] = {{acc00, acc01}, {acc10, acc11}};
#pragma unroll
    for (int mt = 0; mt < 2; mt++)
#pragma unroll
        for (int nt = 0; nt < 2; nt++) {
            float vb = nt ? vb1 : vb0;
#pragma unroll
            for (int i = 0; i < 4; i++) {
                int gm = m0 + wm + mt * 16 + cr + i;
                int gn = n0 + wn + nt * 16 + cc;
                float v = accs[mt][nt][i] + vb;
                if (RELU) v = fmaxf(v, 0.f);
                if (OM == 1) ((bf16*)Cv)[(size_t)gm * ldc + gn] = (bf16)v;
                else         ((float*)Cv)[(size_t)gm * ldc + gn] = v;
            }
        }
}

// ---------------------------------------------------------------------------
// PNA front: pdps (1024 blks) + qgemm (2048 blks) + gh GEMM (384 blks) in ONE
// launch — all three depend only on out_bf / eaord (available at layer start).
// ---------------------------------------------------------------------------
__global__ __launch_bounds__(256) void k_pna_front(
    const bf16* __restrict__ out_bf, const bf16* __restrict__ Wnode_l,
    const float* __restrict__ bcombx_l, float* __restrict__ Pd, bf16* __restrict__ Ps,
    const bf16* __restrict__ eaord, const bf16* __restrict__ wcomb_l,
    bf16* __restrict__ Qord,
    const bf16* __restrict__ Whh, const float* __restrict__ bhh,
    float* __restrict__ gh)
{
    __shared__ char smem[46080];
    const int b = blockIdx.x;
    const int tid = threadIdx.x, wave = tid >> 6, lane = tid & 63;
    const int fr = lane & 15, fk = (lane >> 4) * 8;
    const int cc = lane & 15, cr = (lane >> 4) * 4;

    if (b < 1024 || b >= 3072) {
        // ---- 64x64 GEMM (pdps or gh), K=128 ----
        bf16 (*As)[40] = (bf16 (*)[40])smem;
        bf16 (*Ws)[40] = (bf16 (*)[40])(smem + 5120);
        const bool isGh = (b >= 3072);
        int m0, n0;
        const bf16* W;
        const float* bias;
        bool isPd = false;
        if (isGh) {
            int g = b - 3072;
            m0 = (g & 63) * 64; n0 = (g >> 6) * 64;
            W = Whh; bias = bhh;
        } else {
            m0 = (b & 63) * 64;
            int y = b >> 6;
            isPd = y < 8;
            n0 = (isPd ? y : y - 8) * 64;
            W = Wnode_l + (isPd ? 0 : (size_t)512 * 128);
            bias = bcombx_l;
        }
        const int wm = (wave & 1) * 32, wn = (wave >> 1) * 32;
        const int lrow = tid >> 2, lcol = (tid & 3) * 8;
        floatx4 acc00 = {0,0,0,0}, acc01 = {0,0,0,0}, acc10 = {0,0,0,0}, acc11 = {0,0,0,0};
        for (int k0 = 0; k0 < 128; k0 += 32) {
            bf16x8 av = *(const bf16x8*)(out_bf + (size_t)(m0 + lrow) * 128 + k0 + lcol);
            bf16x8 wv = *(const bf16x8*)(W + (size_t)(n0 + lrow) * 128 + k0 + lcol);
            __syncthreads();
            *(bf16x8*)&As[lrow][lcol] = av;
            *(bf16x8*)&Ws[lrow][lcol] = wv;
            __syncthreads();
            bf16x8 a0 = *(const bf16x8*)&As[wm + fr][fk];
            bf16x8 a1 = *(const bf16x8*)&As[wm + 16 + fr][fk];
            bf16x8 b0 = *(const bf16x8*)&Ws[wn + fr][fk];
            bf16x8 b1 = *(const bf16x8*)&Ws[wn + 16 + fr][fk];
            acc00 = __builtin_amdgcn_mfma_f32_16x16x32_bf16(a0, b0, acc00, 0, 0, 0);
            acc01 = __builtin_amdgcn_mfma_f32_16x16x32_bf16(a0, b1, acc01, 0, 0, 0);
            acc10 = __builtin_amdgcn_mfma_f32_16x16x32_bf16(a1, b0, acc10, 0, 0, 0);
            acc11 = __builtin_amdgcn_mfma_f32_16x16x32_bf16(a1, b1, acc11, 0, 0, 0);
        }
        float vb0 = (isGh || isPd) ? bias[n0 + wn + cc] : 0.f;
        float vb1 = (isGh || isPd) ? bias[n0 + wn + 16 + cc] : 0.f;
        floatx4 accs[2][2] = {{acc00, acc01}, {acc10, acc11}};
#pragma unroll
        for (int mt = 0; mt < 2; mt++)
#pragma unroll
            for (int nt = 0; nt < 2; nt++) {
                float vb = nt ? vb1 : vb0;
#pragma unroll
                for (int i = 0; i < 4; i++) {
                    int gm = m0 + wm + mt * 16 + cr + i;
                    int gn = n0 + wn + nt * 16 + cc;
                    float v = accs[mt][nt][i] + vb;
                    if (isGh)      gh[(size_t)gm * 384 + gn] = v;
                    else if (isPd) Pd[(size_t)gm * 512 + gn] = v;
                    else           Ps[(size_t)gm * 512 + gn] = (bf16)v;
                }
            }
    } else {
        // ---- qgemm: Q_ord[E,512] = eaord[E,64] @ wcomb[512,64]^T ----
        bf16 (*As)[72] = (bf16 (*)[72])smem;               // 64x72x2 = 9216
        bf16 (*Ws)[72] = (bf16 (*)[72])(smem + 9216);      // 256x72x2 = 36864
        int q = b - 1024;
        const int e0 = (q & 1023) * 64, n0g = (q >> 10) * 256;
#pragma unroll
        for (int v = 0; v < 2; v++) {
            int lin = v * 2048 + tid * 8;
            int r = lin >> 6, c = lin & 63;
            *(bf16x8*)&As[r][c] = *(const bf16x8*)(eaord + (size_t)(e0 + r) * 64 + c);
        }
#pragma unroll
        for (int v = 0; v < 8; v++) {
            int lin = v * 2048 + tid * 8;
            int r = lin >> 6, c = lin & 63;
            *(bf16x8*)&Ws[r][c] = *(const bf16x8*)(wcomb_l + (size_t)(n0g + r) * 64 + c);
        }
        __syncthreads();

        floatx4 acc[4][4];
#pragma unroll
        for (int mt = 0; mt < 4; mt++)
#pragma unroll
            for (int nt = 0; nt < 4; nt++) acc[mt][nt] = (floatx4){0,0,0,0};

#pragma unroll
        for (int kk = 0; kk < 64; kk += 32) {
            bf16x8 af[4], bv[4];
#pragma unroll
            for (int mt = 0; mt < 4; mt++) af[mt] = *(const bf16x8*)&As[mt * 16 + fr][kk + fk];
#pragma unroll
            for (int nt = 0; nt < 4; nt++) bv[nt] = *(const bf16x8*)&Ws[wave * 64 + nt * 16 + fr][kk + fk];
#pragma unroll
            for (int mt = 0; mt < 4; mt++)
#pragma unroll
                for (int nt = 0; nt < 4; nt++)
                    acc[mt][nt] = __builtin_amdgcn_mfma_f32_16x16x32_bf16(af[mt], bv[nt], acc[mt][nt], 0, 0, 0);
        }
#pragma unroll
        for (int mt = 0; mt < 4; mt++)
#pragma unroll
            for (int nt = 0; nt < 4; nt++)
#pragma unroll
                for (int i = 0; i < 4; i++) {
                    int row = mt * 16 + cr + i;
                    int col = n0g + wave * 64 + nt * 16 + cc;
                    Qord[(size_t)(e0 + row) * 512 + col] = (bf16)acc[mt][nt][i];
                }
    }
}

// ---------------------------------------------------------------------------
// Fused gi GEMM + GRU elementwise. Each wave computes a 16-row x 384-col gi
// strip (24 accumulator tiles): tiles j, j+8, j+16 hold (ir,iz,ic) for the
// SAME lane/element → GRU gates evaluated entirely in registers. gi never
// touches memory (identical f32 values to the old global round-trip).
// grid 256 blocks x 64 threads (1 wave, 16 rows each).
// ---------------------------------------------------------------------------
__global__ __launch_bounds__(64) void k_gigru(
    const bf16* __restrict__ m_bf, const bf16* __restrict__ Wih,
    const float* __restrict__ bih, const float* __restrict__ gh,
    float* __restrict__ hst, bf16* __restrict__ ob, float* __restrict__ fo)
{
    const int lane = threadIdx.x;
    const int r0 = blockIdx.x * 16;
    const int fr = lane & 15, fk = (lane >> 4) * 8;
    const int cc = lane & 15, cr = (lane >> 4) * 4;
    floatx4 acc[24];
#pragma unroll
    for (int t = 0; t < 24; t++) acc[t] = (floatx4){0, 0, 0, 0};

    for (int k0 = 0; k0 < 128; k0 += 32) {
        bf16x8 a = *(const bf16x8*)(m_bf + (size_t)(r0 + fr) * 128 + k0 + fk);
#pragma unroll
        for (int nt = 0; nt < 24; nt++) {
            bf16x8 b = *(const bf16x8*)(Wih + (size_t)(nt * 16 + fr) * 128 + k0 + fk);
            acc[nt] = __builtin_amdgcn_mfma_f32_16x16x32_bf16(a, b, acc[nt], 0, 0, 0);
        }
    }
#pragma unroll
    for (int j = 0; j < 8; j++) {
        int col = cc + 16 * j;
        float bir = bih[col], biz = bih[col + 128], bic = bih[col + 256];
#pragma unroll
        for (int i = 0; i < 4; i++) {
            int row = r0 + cr + i;
            float ir = acc[j][i]      + bir;
            float iz = acc[j + 8][i]  + biz;
            float ic = acc[j + 16][i] + bic;
            float hr = gh[(size_t)row * 384 + col];
            float hz = gh[(size_t)row * 384 + col + 128];
            float hc = gh[(size_t)row * 384 + col + 256];
            float r = 1.f / (1.f + __expf(-(ir + hr)));
            float z = 1.f / (1.f + __expf(-(iz + hz)));
            float c = tanhf(ic + r * hc);
            size_t idx = (size_t)row * 128 + col;
            float h = hst[idx];
            float hn = (1.f - z) * c + z * h;
            hst[idx] = hn;
            ob[idx] = (bf16)hn;
            if (fo) { fo[idx] = hn; fo[4718592 + idx] = hn; }
        }
    }
}

// ---------------------------------------------------------------------------
// Fused edge update — REVERTED to R8 (validated): per-k-step A gather + LDS
// weight staging + T14 register prefetch (cross-stage pipelined).
// LDS 53248 B → 3 blocks/CU. R9's direct-operand variant regressed (lost
// coalescing: 12x scattered 16B loads/wave/k-step, 2x duplicated) — staging
// is load-bearing here.
// ---------------------------------------------------------------------------
__global__ __launch_bounds__(256) void k_edge(
    const bf16* __restrict__ SAB,
    const bf16* __restrict__ em2W, const float* __restrict__ em2b,
    const bf16* __restrict__ eu1W, const float* __restrict__ eu1b,
    const bf16* __restrict__ eu2W, const float* __restrict__ eu2b,
    const int* __restrict__ src, const int* __restrict__ dst,
    const int* __restrict__ pos,
    bf16* __restrict__ eaord, float* __restrict__ ea_out_f)
{
    __shared__ char smem[53248];
    bf16 (*Ws)[40]   = (bf16 (*)[40])smem;                 // 128x40 = 10240 B
    bf16 (*med)[200] = (bf16 (*)[200])(smem + 10240);      // 64x200 = 25600 B
    bf16 (*As)[40]   = (bf16 (*)[40])(smem + 35840);       // 64x40 = 5120 B (stage 1; aliases t2s)
    bf16 (*t2s)[136] = (bf16 (*)[136])(smem + 35840);      // 64x136 = 17408 B (stages 2-3)

    const int e0 = blockIdx.x * 64;
    const int tid = threadIdx.x, wave = tid >> 6, lane = tid & 63;
    const int lrow = tid >> 2, lcol = (tid & 3) * 8;
    const int fr = lane & 15, fk = (lane >> 4) * 8;
    const int cc = lane & 15, cr = (lane >> 4) * 4;
    const int wr = tid & 127, wc = (tid >> 7) * 16;        // stage 1/2 W loader
    const int wr3 = tid & 63, wc3 = (tid >> 6) * 8;        // stage 3 W loader
    const int sI = src[e0 + lrow], dI = dst[e0 + lrow];
    const floatx4 z4 = {0.f, 0.f, 0.f, 0.f};

    // early gather: ea append tile (consumed at end of stage 1)
    const int ac0 = (tid & 3) * 16;
    const int apr = pos[e0 + lrow];
    bf16x8 ea0 = *(const bf16x8*)(eaord + (size_t)apr * 64 + ac0);
    bf16x8 ea1 = *(const bf16x8*)(eaord + (size_t)apr * 64 + ac0 + 8);

    // ---------- stage 1: m_ed = relu(A @ em2W^T + em2b)  [64x128, K=256] ----------
    const int wm1 = (wave & 1) * 32, wn1 = (wave >> 1) * 64;
    floatx4 acc1[2][4];
#pragma unroll
    for (int mt = 0; mt < 2; mt++)
#pragma unroll
        for (int nt = 0; nt < 4; nt++) acc1[mt][nt] = z4;

    // prologue prefetch (k0 = 0)
    bf16x8 sv = *(const bf16x8*)(SAB + (size_t)sI * 512 + lcol);
    bf16x8 dv = *(const bf16x8*)(SAB + (size_t)dI * 512 + 256 + lcol);
    bf16x8 w0 = *(const bf16x8*)(em2W + (size_t)wr * 256 + wc);
    bf16x8 w1 = *(const bf16x8*)(em2W + (size_t)wr * 256 + wc + 8);

    for (int k0 = 0; k0 < 256; k0 += 32) {
        __syncthreads();
        bf16 a8[8];
#pragma unroll
        for (int j = 0; j < 8; j++)
            a8[j] = (bf16)fmaxf((float)sv[j] + (float)dv[j], 0.f);
        *(bf16x8*)&As[lrow][lcol] = *(bf16x8*)a8;
        *(bf16x8*)&Ws[wr][wc]     = w0;
        *(bf16x8*)&Ws[wr][wc + 8] = w1;
        int kn = k0 + 32;
        if (kn < 256) {
            sv = *(const bf16x8*)(SAB + (size_t)sI * 512 + kn + lcol);
            dv = *(const bf16x8*)(SAB + (size_t)dI * 512 + 256 + kn + lcol);
            w0 = *(const bf16x8*)(em2W + (size_t)wr * 256 + kn + wc);
            w1 = *(const bf16x8*)(em2W + (size_t)wr * 256 + kn + wc + 8);
        } else {
            // cross-stage prefetch: stage-2's first weight slice
            w0 = *(const bf16x8*)(eu1W + (size_t)wr * 192 + wc);
            w1 = *(const bf16x8*)(eu1W + (size_t)wr * 192 + wc + 8);
        }
        __syncthreads();
        bf16x8 af[2], bv[4];
        af[0] = *(const bf16x8*)&As[wm1 + fr][fk];
        af[1] = *(const bf16x8*)&As[wm1 + 16 + fr][fk];
#pragma unroll
        for (int nt = 0; nt < 4; nt++) bv[nt] = *(const bf16x8*)&Ws[wn1 + nt * 16 + fr][fk];
#pragma unroll
        for (int mt = 0; mt < 2; mt++)
#pragma unroll
            for (int nt = 0; nt < 4; nt++)
                acc1[mt][nt] = __builtin_amdgcn_mfma_f32_16x16x32_bf16(af[mt], bv[nt], acc1[mt][nt], 0, 0, 0);
    }
    // med region is disjoint from As/Ws — no barrier needed before these writes
#pragma unroll
    for (int mt = 0; mt < 2; mt++)
#pragma unroll
        for (int nt = 0; nt < 4; nt++)
#pragma unroll
            for (int i = 0; i < 4; i++) {
                int row = wm1 + mt * 16 + cr + i;
                int col = wn1 + nt * 16 + cc;
                med[row][col] = (bf16)fmaxf(acc1[mt][nt][i] + em2b[col], 0.f);
            }
    // append ea tile from the early-gathered registers
    *(bf16x8*)&med[lrow][128 + ac0]     = ea0;
    *(bf16x8*)&med[lrow][128 + ac0 + 8] = ea1;
    // med-ready sync provided by stage-2's first in-loop barrier

    // ---------- stage 2: t2 = relu([m_ed|ea] @ eu1W^T + eu1b)  [64x128, K=192] ----------
    floatx4 acc2[2][4];
#pragma unroll
    for (int mt = 0; mt < 2; mt++)
#pragma unroll
        for (int nt = 0; nt < 4; nt++) acc2[mt][nt] = z4;

    for (int k0 = 0; k0 < 192; k0 += 32) {
        __syncthreads();
        *(bf16x8*)&Ws[wr][wc]     = w0;
        *(bf16x8*)&Ws[wr][wc + 8] = w1;
        int kn = k0 + 32;
        if (kn < 192) {
            w0 = *(const bf16x8*)(eu1W + (size_t)wr * 192 + kn + wc);
            w1 = *(const bf16x8*)(eu1W + (size_t)wr * 192 + kn + wc + 8);
        } else {
            // cross-stage prefetch: stage-3's first weight slice
            w0 = *(const bf16x8*)(eu2W + (size_t)wr3 * 128 + wc3);
        }
        __syncthreads();
        bf16x8 af[2], bv[4];
        af[0] = *(const bf16x8*)&med[wm1 + fr][k0 + fk];
        af[1] = *(const bf16x8*)&med[wm1 + 16 + fr][k0 + fk];
#pragma unroll
        for (int nt = 0; nt < 4; nt++) bv[nt] = *(const bf16x8*)&Ws[wn1 + nt * 16 + fr][fk];
#pragma unroll
        for (int mt = 0; mt < 2; mt++)
#pragma unroll
            for (int nt = 0; nt < 4; nt++)
                acc2[mt][nt] = __builtin_amdgcn_mfma_f32_16x16x32_bf16(af[mt], bv[nt], acc2[mt][nt], 0, 0, 0);
    }
    // t2s aliases As (dead since end of stage 1); disjoint from med and Ws
#pragma unroll
    for (int mt = 0; mt < 2; mt++)
#pragma unroll
        for (int nt = 0; nt < 4; nt++)
#pragma unroll
            for (int i = 0; i < 4; i++) {
                int row = wm1 + mt * 16 + cr + i;
                int col = wn1 + nt * 16 + cc;
                t2s[row][col] = (bf16)fmaxf(acc2[mt][nt][i] + eu1b[col], 0.f);
            }
    // t2s-ready sync provided by stage-3's first in-loop barrier

    // ---------- stage 3: ea' = t2 @ eu2W^T + eu2b  [64x64, K=128] ----------
    const int wm3 = (wave & 1) * 32, wn3 = (wave >> 1) * 32;
    floatx4 acc3[2][2];
#pragma unroll
    for (int mt = 0; mt < 2; mt++)
#pragma unroll
        for (int nt = 0; nt < 2; nt++) acc3[mt][nt] = z4;

    for (int k0 = 0; k0 < 128; k0 += 32) {
        __syncthreads();
        *(bf16x8*)&Ws[wr3][wc3] = w0;
        int kn = k0 + 32;
        if (kn < 128)
            w0 = *(const bf16x8*)(eu2W + (size_t)wr3 * 128 + kn + wc3);
        __syncthreads();
        bf16x8 af[2], bv[2];
        af[0] = *(const bf16x8*)&t2s[wm3 + fr][k0 + fk];
        af[1] = *(const bf16x8*)&t2s[wm3 + 16 + fr][k0 + fk];
#pragma unroll
        for (int nt = 0; nt < 2; nt++) bv[nt] = *(const bf16x8*)&Ws[wn3 + nt * 16 + fr][fk];
#pragma unroll
        for (int mt = 0; mt < 2; mt++)
#pragma unroll
            for (int nt = 0; nt < 2; nt++)
                acc3[mt][nt] = __builtin_amdgcn_mfma_f32_16x16x32_bf16(af[mt], bv[nt], acc3[mt][nt], 0, 0, 0);
    }
#pragma unroll
    for (int mt = 0; mt < 2; mt++)
#pragma unroll
        for (int nt = 0; nt < 2; nt++)
#pragma unroll
            for (int i = 0; i < 4; i++) {
                int row = wm3 + mt * 16 + cr + i;
                int col = wn3 + nt * 16 + cc;
                float v = acc3[mt][nt][i] + eu2b[col];
                int e = e0 + row;
                eaord[(size_t)pos[e] * 64 + col] = (bf16)v;
                if (ea_out_f) ea_out_f[(size_t)e * 64 + col] = v;  // final layer only
            }
}

// ---------------------------------------------------------------------------
// Post-MLP per-tower MFMA GEMM — consumes bf16 agg buffers
// ---------------------------------------------------------------------------
__global__ __launch_bounds__(256) void k_postg(
    const bf16* __restrict__ xin, const bf16* __restrict__ aggX,
    const bf16* __restrict__ aggS, const bf16* __restrict__ aggM,
    const bf16* __restrict__ qWbf, const float* __restrict__ qb,
    bf16* __restrict__ ybf)
{
    __shared__ bf16 As[64][40];
    __shared__ bf16 Ws[32][40];
    const int n0 = blockIdx.x * 64, t = blockIdx.y;
    const int tid = threadIdx.x, wave = tid >> 6, lane = tid & 63;
    const int lrow = tid >> 2, lcol = (tid & 3) * 8;
    const int fr = lane & 15, fk = (lane >> 4) * 8;
    floatx4 acc0 = {0,0,0,0}, acc1 = {0,0,0,0};

    for (int k0 = 0; k0 < 512; k0 += 32) {
        int n = n0 + lrow;
        int c0 = k0 + lcol;
        const bf16* srcp;
        if (c0 < 128)      srcp = xin  + (size_t)n * 128 + c0;
        else if (c0 < 256) srcp = aggX + (size_t)n * 512 + t * 128 + (c0 - 128);
        else if (c0 < 384) srcp = aggS + (size_t)n * 512 + t * 128 + (c0 - 256);
        else               srcp = aggM + (size_t)n * 512 + t * 128 + (c0 - 384);
        bf16x8 a8 = *(const bf16x8*)srcp;
        bf16 w8[8];
        if (tid < 128) {
            int wr = tid >> 2, wc = (tid & 3) * 8;
            *(bf16x8*)w8 = *(const bf16x8*)(qWbf + (size_t)(t * 32 + wr) * 512 + k0 + wc);
        }
        __syncthreads();
        *(bf16x8*)&As[lrow][lcol] = a8;
        if (tid < 128) {
            int wr = tid >> 2, wc = (tid & 3) * 8;
            *(bf16x8*)&Ws[wr][wc] = *(bf16x8*)w8;
        }
        __syncthreads();
        bf16x8 a  = *(const bf16x8*)&As[wave * 16 + fr][fk];
        bf16x8 b0 = *(const bf16x8*)&Ws[fr][fk];
        bf16x8 b1 = *(const bf16x8*)&Ws[16 + fr][fk];
        acc0 = __builtin_amdgcn_mfma_f32_16x16x32_bf16(a, b0, acc0, 0, 0, 0);
        acc1 = __builtin_amdgcn_mfma_f32_16x16x32_bf16(a, b1, acc1, 0, 0, 0);
    }
    const int cc = lane & 15, cr = (lane >> 4) * 4;
#pragma unroll
    for (int i = 0; i < 4; i++) {
        int gn = n0 + wave * 16 + cr + i;
        ybf[(size_t)gn * 128 + t * 32 + cc]      = (bf16)(acc0[i] + qb[t * 32 + cc]);
        ybf[(size_t)gn * 128 + t * 32 + 16 + cc] = (bf16)(acc1[i] + qb[t * 32 + 16 + cc]);
    }
}

// ----------------------- CSR scan / fill ------------------------------------
__global__ __launch_bounds__(1024) void k_scan(
    const int* __restrict__ counts, int* __restrict__ offs, int* __restrict__ cursor)
{
    __shared__ int ls[1024];
    int tid = threadIdx.x, base = tid * 4;
    int c0 = counts[base], c1 = counts[base + 1], c2 = counts[base + 2], c3 = counts[base + 3];
    ls[tid] = c0 + c1 + c2 + c3;
    __syncthreads();
    for (int d = 1; d < 1024; d <<= 1) {
        int v = (tid >= d) ? ls[tid - d] : 0;
        __syncthreads();
        ls[tid] += v;
        __syncthreads();
    }
    int r = tid ? ls[tid - 1] : 0;
    offs[base] = r;     cursor[base] = r;     r += c0;
    offs[base + 1] = r; cursor[base + 1] = r; r += c1;
    offs[base + 2] = r; cursor[base + 2] = r; r += c2;
    offs[base + 3] = r; cursor[base + 3] = r; r += c3;
    if (tid == 1023) offs[4096] = r;
}

__global__ void k_fill(const int* __restrict__ dst, const int* __restrict__ srcW,
                       int* __restrict__ cursor, int* __restrict__ pos,
                       int* __restrict__ srcord)
{
    int e = blockIdx.x * 256 + threadIdx.x;
    int p = atomicAdd(&cursor[dst[e]], 1);
    pos[e] = p;
    srcord[p] = srcW[e];
}

// ---------------------------------------------------------------------------
// Single-pass aggregation. Pd f32 (own row, sequential); Ps bf16 L2-resident.
// ---------------------------------------------------------------------------
__global__ __launch_bounds__(128) void k_agg(
    const float* __restrict__ Pd, const bf16* __restrict__ Ps,
    const bf16* __restrict__ Qord,
    const int* __restrict__ srcord, const int* __restrict__ offs,
    bf16* __restrict__ aggX, bf16* __restrict__ aggS, bf16* __restrict__ aggM)
{
    int n = blockIdx.x, tid = threadIdx.x;
    int c = tid * 4;
    float4 pd = *(const float4*)(Pd + (size_t)n * 512 + c);
    float s0 = 0, s1 = 0, s2 = 0, s3 = 0;
    float q0 = 0, q1 = 0, q2 = 0, q3 = 0;
    float x0 = -3e38f, x1 = -3e38f, x2 = -3e38f, x3 = -3e38f;
    int beg = offs[n], end = offs[n + 1];
    for (int i = beg; i < end; i++) {
        int sn = srcord[i];
        bf16x4 psv = *(const bf16x4*)(Ps + (size_t)sn * 512 + c);
        bf16x4 qv  = *(const bf16x4*)(Qord + (size_t)i * 512 + c);
        float m0 = pd.x + (float)psv[0] + (float)qv[0];
        float m1 = pd.y + (float)psv[1] + (float)qv[1];
        float m2 = pd.z + (float)psv[2] + (float)qv[2];
        float m3 = pd.w + (float)psv[3] + (float)qv[3];
        s0 += m0; s1 += m1; s2 += m2; s3 += m3;
        q0 += m0 * m0; q1 += m1 * m1; q2 += m2 * m2; q3 += m3 * m3;
        x0 = fmaxf(x0, m0); x1 = fmaxf(x1, m1); x2 = fmaxf(x2, m2); x3 = fmaxf(x3, m3);
    }
    int cnt = end - beg;
    float inv = 1.f / fmaxf((float)cnt, 1.f);
    float me0 = s0 * inv, me1 = s1 * inv, me2 = s2 * inv, me3 = s3 * inv;
    float v0 = fmaxf(q0 * inv - me0 * me0, 0.f);
    float v1 = fmaxf(q1 * inv - me1 * me1, 0.f);
    float v2 = fmaxf(q2 * inv - me2 * me2, 0.f);
    float v3 = fmaxf(q3 * inv - me3 * me3, 0.f);
    size_t o = (size_t)n * 512 + c;
    bf16x4 mx, st, me;
    mx[0] = (bf16)(cnt > 0 ? x0 : 0.f); mx[1] = (bf16)(cnt > 0 ? x1 : 0.f);
    mx[2] = (bf16)(cnt > 0 ? x2 : 0.f); mx[3] = (bf16)(cnt > 0 ? x3 : 0.f);
    st[0] = (bf16)sqrtf(v0 + 1e-5f); st[1] = (bf16)sqrtf(v1 + 1e-5f);
    st[2] = (bf16)sqrtf(v2 + 1e-5f); st[3] = (bf16)sqrtf(v3 + 1e-5f);
    me[0] = (bf16)me0; me[1] = (bf16)me1; me[2] = (bf16)me2; me[3] = (bf16)me3;
    *(bf16x4*)(aggX + o) = mx;
    *(bf16x4*)(aggS + o) = st;
    *(bf16x4*)(aggM + o) = me;
}

__global__ void k_sentinel(float* __restrict__ o, float v)
{
    int i = blockIdx.x * 256 + threadIdx.x;
    o[i] = v;
}

// ===========================================================================
extern "C" void kernel_launch(void* const* d_in, const int* in_sizes, int n_in,
                              void* d_out, int out_size, void* d_ws, size_t ws_size,
                              hipStream_t stream)
{
    static const int exp_sizes[23] = {
        524288, 4194304, 131072, 24576, 384, 589824, 1536, 196608, 384,
        49152, 384, 49152, 49152, 384, 384, 65536, 256, 32768, 128,
        24576, 128, 8192, 64 };
    if (n_in != 23) { k_sentinel<<<2048, 256, 0, stream>>>((float*)d_out, 200.f); return; }
    for (int i = 0; i < 23; i++)
        if (in_sizes[i] != exp_sizes[i]) {
            k_sentinel<<<2048, 256, 0, stream>>>((float*)d_out, 60.f + 4.f * i);
            return;
        }
    if (out_size != 5242880) { k_sentinel<<<2048, 256, 0, stream>>>((float*)d_out, 52.f); return; }

    const int* eidx = (const int*)d_in[2];

    char* w = (char*)d_ws;
    size_t off = 0;
    auto alloc = [&](size_t bytes) -> char* {
        char* p = w + off;
        off = (off + bytes + 255) & ~(size_t)255;
        return p;
    };
    int*   dflag   = (int*)  alloc(256);
    int*   iflag   = (int*)  alloc(256);
    int*   srcW    = (int*)  alloc((size_t)EE * 4);
    int*   dstW    = (int*)  alloc((size_t)EE * 4);
    int*   pos     = (int*)  alloc((size_t)EE * 4);
    int*   srcord  = (int*)  alloc((size_t)EE * 4);
    float* out_f32 = (float*)alloc((size_t)NN * HH * 4);
    bf16*  out_bf  = (bf16*) alloc((size_t)NN * HH * 2);
    bf16*  m_bf    = (bf16*) alloc((size_t)NN * HH * 2);
    bf16*  ybf     = (bf16*) alloc((size_t)NN * HH * 2);
    bf16*  eaord   = (bf16*) alloc((size_t)EE * EDD * 2);
    bf16*  wcombAll= (bf16*) alloc((size_t)3 * THD * EDD * 2);
    float* bcombAll= (float*)alloc((size_t)3 * 1024 * 4);
    int*   counts  = (int*)  alloc((size_t)NN * 4);
    int*   offs    = (int*)  alloc((size_t)(NN + 1) * 4);
    int*   cursor  = (int*)  alloc((size_t)NN * 4);
    float* Pd      = (float*)alloc((size_t)NN * THD * 4);   // [4096,512] f32
    bf16*  Ps      = (bf16*) alloc((size_t)NN * THD * 2);   // [4096,512] bf16 (L2-resident)
    bf16*  aggX    = (bf16*) alloc((size_t)NN * THD * 2);
    bf16*  aggS    = (bf16*) alloc((size_t)NN * THD * 2);
    bf16*  aggM    = (bf16*) alloc((size_t)NN * THD * 2);
    float* ghB     = (float*)alloc((size_t)NN * 384 * 4);
    float* encWc  = (float*)alloc((size_t)24576 * 4);
    float* encbc  = (float*)alloc((size_t)384 * 4);
    float* preWc  = (float*)alloc((size_t)589824 * 4);
    float* prebc  = (float*)alloc((size_t)1536 * 4);
    float* postbc = (float*)alloc((size_t)384 * 4);
    float* linbc  = (float*)alloc((size_t)384 * 4);
    float* bihc   = (float*)alloc((size_t)384 * 4);
    float* bhhc   = (float*)alloc((size_t)384 * 4);
    float* em1bc  = (float*)alloc((size_t)256 * 4);
    float* em1ext = (float*)alloc((size_t)512 * 4);
    float* em2bc  = (float*)alloc((size_t)128 * 4);
    float* eu1bc  = (float*)alloc((size_t)128 * 4);
    float* eu2bc  = (float*)alloc((size_t)64 * 4);
    bf16* preWbf = (bf16*)alloc((size_t)589824 * 2);
    bf16* WnodeBf= (bf16*)alloc((size_t)3 * 131072 * 2);
    bf16* postWbf= (bf16*)alloc((size_t)196608 * 2);
    bf16* linWbf = (bf16*)alloc((size_t)49152 * 2);
    bf16* WihBf  = (bf16*)alloc((size_t)49152 * 2);
    bf16* WhhBf  = (bf16*)alloc((size_t)49152 * 2);
    bf16* em1Wbf = (bf16*)alloc((size_t)65536 * 2);
    bf16* Wem1Bf = (bf16*)alloc((size_t)65536 * 2);
    bf16* em2Wbf = (bf16*)alloc((size_t)32768 * 2);
    bf16* eu1Wbf = (bf16*)alloc((size_t)24576 * 2);
    bf16* eu2Wbf = (bf16*)alloc((size_t)8192 * 2);
    // phase-shared region: Q_ord (PNA) / SAB (edge, bf16)
    char* region = alloc((size_t)EE * 512 * 2);     // 67.1 MB
    bf16*  Qord = (bf16*) (region);
    bf16*  SAB  = (bf16*) (region);                 // [N,512] bf16 = 4.2 MB

    if (ws_size < off) { k_sentinel<<<2048, 256, 0, stream>>>((float*)d_out, 44.f); return; }

    // ---- setup: detect+zero / extidx+count / scan / fill ----
    k_det0<<<18, 256, 0, stream>>>(d_in[1], eidx, dflag, iflag, counts);
    k_extcnt<<<EE / 256, 256, 0, stream>>>(eidx, srcW, dstW, iflag, counts);
    k_scan<<<1, 1024, 0, stream>>>(counts, offs, cursor);
    k_fill<<<EE / 256, 256, 0, stream>>>(dstW, srcW, cursor, pos, srcord);

    // ---- ONE mega-canon launch ----
    {
        JobTab tab;
        int bi = 0, ji = 0;
        auto add = [&](const void* s, void* d1, void* d2, int n, int mode) {
            tab.j[ji] = { s, d1, d2, n, mode, bi };
            bi += (n + 255) / 256;
            ji++;
        };
        add(d_in[0],  out_f32, out_bf, 524288, 2);
        add(d_in[1],  eaord,   nullptr, 4194304, 3);
        add(d_in[5],  preWc,   preWbf, 589824, 2);
        add(d_in[3],  encWc,   nullptr, 24576, 0);
        add(d_in[4],  encbc,   nullptr, 384, 0);
        add(d_in[6],  prebc,   nullptr, 1536, 0);
        add(d_in[8],  postbc,  nullptr, 384, 0);
        add(d_in[10], linbc,   nullptr, 384, 0);
        add(d_in[13], bihc,    nullptr, 384, 0);
        add(d_in[14], bhhc,    nullptr, 384, 0);
        add(d_in[16], em1bc,   nullptr, 256, 0);
        add(d_in[18], em2bc,   nullptr, 128, 0);
        add(d_in[20], eu1bc,   nullptr, 128, 0);
        add(d_in[22], eu2bc,   nullptr, 64, 0);
        add(d_in[7],  postWbf, nullptr, 196608, 1);
        add(d_in[9],  linWbf,  nullptr, 49152, 1);
        add(d_in[11], WihBf,   nullptr, 49152, 1);
        add(d_in[12], WhhBf,   nullptr, 49152, 1);
        add(d_in[15], em1Wbf,  nullptr, 65536, 1);
        add(d_in[17], em2Wbf,  nullptr, 32768, 1);
        add(d_in[19], eu1Wbf,  nullptr, 24576, 1);
        add(d_in[21], eu2Wbf,  nullptr, 8192, 1);
        k_canon_all<<<bi, 256, 0, stream>>>(tab, dflag, pos);
    }
    // ---- fused repacks + all-layer wcomb ----
    k_setup2<<<2178, 256, 0, stream>>>(preWbf, em1Wbf, em1bc, WnodeBf, Wem1Bf, em1ext,
                                       preWc, encWc, encbc, prebc, wcombAll, bcombAll);

    auto GEMM = [&](const bf16* A, int lda, const bf16* Wm, int ldw, const float* bias,
                    void* C, int ldc, int M, int Nout, int K, bool relu, int om) {
        dim3 grid(M / 64, Nout / 64);
        if (relu) {
            if (om) k_mgemm<true, 1><<<grid, 256, 0, stream>>>(A, lda, Wm, ldw, bias, C, ldc, K);
            else    k_mgemm<true, 0><<<grid, 256, 0, stream>>>(A, lda, Wm, ldw, bias, C, ldc, K);
        } else {
            if (om) k_mgemm<false, 1><<<grid, 256, 0, stream>>>(A, lda, Wm, ldw, bias, C, ldc, K);
            else    k_mgemm<false, 0><<<grid, 256, 0, stream>>>(A, lda, Wm, ldw, bias, C, ldc, K);
        }
    };

    for (int l = 0; l < 3; l++) {
        const bf16*  Wnode_l  = WnodeBf + (size_t)l * 131072;
        const bf16*  postW_l  = postWbf + (size_t)l * 65536;
        const float* postb_l  = postbc + (size_t)l * 128;
        const bf16*  linW_l   = linWbf + (size_t)l * 16384;
        const float* linb_l   = linbc  + (size_t)l * 128;
        const bf16*  wcomb_l  = wcombAll + (size_t)l * 32768;
        const float* bcombx_l = bcombAll + (size_t)l * 1024;
        const bool last = (l == 2);

        // ---- PNA front: pdps + qgemm + gh in one launch ----
        k_pna_front<<<3456, 256, 0, stream>>>(out_bf, Wnode_l, bcombx_l, Pd, Ps,
                                              eaord, wcomb_l, Qord, WhhBf, bhhc, ghB);
        k_agg<<<NN, 128, 0, stream>>>(Pd, Ps, Qord, srcord, offs, aggX, aggS, aggM);
        k_postg<<<dim3(NN / 64, 4), 256, 0, stream>>>(out_bf, aggX, aggS, aggM,
                                                      postW_l, postb_l, ybf);
        GEMM(ybf, HH, linW_l, HH, linb_l, m_bf, HH, NN, HH, HH, true, 1);
        // ---- GRU: fused gi GEMM + elementwise (gh precomputed in pna_front) ----
        k_gigru<<<256, 64, 0, stream>>>(m_bf, WihBf, bihc, ghB, out_f32, out_bf,
                                        last ? (float*)d_out : (float*)nullptr);
        // ---- edge update (merged SAB + fused chain; SAB bf16) ----
        GEMM(out_bf, HH, Wem1Bf, 128, em1ext, SAB, 512, NN, 512, HH, false, 1);
        k_edge<<<EE / 64, 256, 0, stream>>>(SAB, em2Wbf, em2bc, eu1Wbf, eu1bc,
                                            eu2Wbf, eu2bc, srcW, dstW, pos,
                                            eaord, last ? (float*)d_out + 524288 : (float*)nullptr);
    }
}

// Round 11
// 444.321 us; speedup vs baseline: 1.1675x; 1.1472x over previous
//
#include <hip/hip_runtime.h>
#include <hip/hip_bf16.h>
#include <math.h>

#define NN 4096
#define EE 65536
#define HH 128
#define EDD 64
#define THD 512

typedef __bf16 bf16;
typedef __bf16 bf16x8 __attribute__((ext_vector_type(8)));
typedef __bf16 bf16x4 __attribute__((ext_vector_type(4)));
typedef float  floatx4 __attribute__((ext_vector_type(4)));

// ---------------------------------------------------------------------------
// Fused setup detect: block 0 = float-dtype detect, block 1 = idx detect,
// blocks 2..17 = zero counts[4096]. One launch replaces 3.
// ---------------------------------------------------------------------------
__global__ __launch_bounds__(256) void k_det0(const void* __restrict__ eaIn,
                                              const int* __restrict__ eidx,
                                              int* __restrict__ dflag,
                                              int* __restrict__ iflag,
                                              int* __restrict__ counts)
{
    int b = blockIdx.x, t = threadIdx.x;
    if (b == 0) {
        if (t < 64) {
            const bf16* p = (const bf16*)eaIn;
            int bad = 0;
            for (int i = 0; i < 32; i++) {
                float v = (float)p[t * 32 + i];
                if (!(v == v) || fabsf(v) > 100.f) bad = 1;
            }
            unsigned long long m = __ballot(bad);
            if (t == 0) *dflag = (m == 0ULL) ? 1 : 0;
        }
    } else if (b == 1) {
        if (t < 64) {
            int bad = 0;
            for (int i = 0; i < 8; i++) {
                int k = t * 8 + i;
                int lo = eidx[2 * k], hi = eidx[2 * k + 1];
                if (hi != 0 || lo < 0 || lo >= NN) bad = 1;
            }
            unsigned long long m = __ballot(bad);
            if (t == 0) *iflag = (m == 0ULL) ? 1 : 0;
        }
    } else {
        counts[(b - 2) * 256 + t] = 0;
    }
}

// extidx + degree count fused
__global__ void k_extcnt(const int* __restrict__ p, int* __restrict__ srcW,
                         int* __restrict__ dstW, const int* __restrict__ iflag,
                         int* __restrict__ counts)
{
    int e = blockIdx.x * 256 + threadIdx.x;
    int s, d;
    if (*iflag) { s = p[2 * e];  d = p[2 * EE + 2 * e]; }
    else        { s = p[e];      d = p[EE + e]; }
    s = min(max(s, 0), NN - 1);
    d = min(max(d, 0), NN - 1);
    srcW[e] = s;
    dstW[e] = d;
    atomicAdd(&counts[d], 1);
}

// ---------------------------------------------------------------------------
// Mega-canonicalize: all dtype-canon jobs in ONE launch.
// modes: 0 = f32 out, 1 = bf16 out, 2 = both, 3 = ea CSR scatter (bf16)
// ---------------------------------------------------------------------------
#define NJOBS 22
struct Job { const void* src; void* dst1; void* dst2; int n; int mode; int blk0; };
struct JobTab { Job j[NJOBS]; };

__global__ __launch_bounds__(256) void k_canon_all(JobTab tab, const int* __restrict__ flag,
                                                   const int* __restrict__ pos)
{
    int b = blockIdx.x;
    int jj = 0;
#pragma unroll
    for (int t = 1; t < NJOBS; t++) if (b >= tab.j[t].blk0) jj = t;
    const Job J = tab.j[jj];
    int i = (b - J.blk0) * 256 + threadIdx.x;
    if (i >= J.n) return;
    float v = (*flag) ? (float)((const bf16*)J.src)[i] : ((const float*)J.src)[i];
    if (J.mode == 0) {
        ((float*)J.dst1)[i] = v;
    } else if (J.mode == 1) {
        ((bf16*)J.dst1)[i] = (bf16)v;
    } else if (J.mode == 2) {
        ((float*)J.dst1)[i] = v;
        ((bf16*)J.dst2)[i] = (bf16)v;
    } else {
        int e = i >> 6, d = i & 63;
        ((bf16*)J.dst1)[(size_t)pos[e] * 64 + d] = (bf16)v;
    }
}

// ---------------------------------------------------------------------------
// Fused post-canon setup: weight repacks (rep_node 1536 | rep_em1 256 |
// ext_em1b 2) + ALL-LAYER wcomb (384 blocks, 4 tf each). One launch.
// ---------------------------------------------------------------------------
__global__ __launch_bounds__(256) void k_setup2(
    const bf16* __restrict__ preWbf, const bf16* __restrict__ em1Wbf,
    const float* __restrict__ em1b,
    bf16* __restrict__ Wnode, bf16* __restrict__ Wem1, float* __restrict__ ext,
    const float* __restrict__ preWc, const float* __restrict__ encWc,
    const float* __restrict__ encbc, const float* __restrict__ prebc,
    bf16* __restrict__ wcombAll, float* __restrict__ bcombAll)
{
    __shared__ float pw[4][128];
    __shared__ float red[4][64];
    int b = blockIdx.x, tid = threadIdx.x;
    if (b < 1536) {                          // rep_node: 3*1024*128 elements
        int i = b * 256 + tid;
        int l = i >> 17, rem = i & 131071;
        int r = rem >> 7, c = rem & 127;
        bf16 v = (r < 512) ? preWbf[(size_t)l * 196608 + (size_t)r * 384 + c]
                           : preWbf[(size_t)l * 196608 + (size_t)(r - 512) * 384 + 128 + c];
        Wnode[i] = v;
    } else if (b < 1792) {                   // rep_em1: 512*128
        int i = (b - 1536) * 256 + tid;
        int r = i >> 7, c = i & 127;
        Wem1[i] = (r < 256) ? em1Wbf[(size_t)r * 256 + c]
                            : em1Wbf[(size_t)(r - 256) * 256 + 128 + c];
    } else if (b < 1794) {                   // ext_em1b: 512
        int i = (b - 1792) * 256 + tid;
        if (i < 512) ext[i] = (i < 256) ? em1b[i] : 0.f;
    } else {                                 // wcomb: 384 blocks x 4 tf
        int q = b - 1794;
        int sub = tid >> 6, d = tid & 63;
        int tf = q * 4 + sub;                // 0..1535
        int l = tf >> 9, tfl = tf & 511;
        const float* pr = preWc + (size_t)l * 196608 + (size_t)tfl * 384 + 256;
        pw[sub][d]      = pr[d];
        pw[sub][d + 64] = pr[d + 64];
        __syncthreads();
        const float* encW = encWc + (size_t)l * 8192;
        float acc = 0.f;
        for (int h = 0; h < 128; h++) acc += pw[sub][h] * encW[h * 64 + d];
        wcombAll[(size_t)l * 32768 + (size_t)tfl * 64 + d] = (bf16)acc;
        float bb = pw[sub][d] * encbc[l * 128 + d] + pw[sub][d + 64] * encbc[l * 128 + 64 + d];
        red[sub][d] = bb;
        __syncthreads();
        for (int s = 32; s > 0; s >>= 1) { if (d < s) red[sub][d] += red[sub][d + s]; __syncthreads(); }
        if (d == 0) {
            bcombAll[l * 1024 + tfl] = red[sub][0] + prebc[l * 512 + tfl];
            bcombAll[l * 1024 + 512 + tfl] = 0.f;
        }
    }
}

// ---------------------------------------------------------------------------
// MFMA bf16 GEMM (validated): C[M,Nout] = act(A @ W^T + bias)
// ---------------------------------------------------------------------------
template<bool RELU, int OM>
__global__ __launch_bounds__(256) void k_mgemm(
    const bf16* __restrict__ A, int lda,
    const bf16* __restrict__ W, int ldw, const float* __restrict__ bias,
    void* __restrict__ Cv, int ldc, int K)
{
    __shared__ bf16 As[64][40];
    __shared__ bf16 Ws[64][40];
    const int m0 = blockIdx.x * 64, n0 = blockIdx.y * 64;
    const int tid = threadIdx.x, wave = tid >> 6, lane = tid & 63;
    const int wm = (wave & 1) * 32, wn = (wave >> 1) * 32;
    const int lrow = tid >> 2, lcol = (tid & 3) * 8;
    const int fr = lane & 15, fk = (lane >> 4) * 8;
    floatx4 acc00 = {0,0,0,0}, acc01 = {0,0,0,0}, acc10 = {0,0,0,0}, acc11 = {0,0,0,0};

    for (int k0 = 0; k0 < K; k0 += 32) {
        bf16x8 av = *(const bf16x8*)(A + (size_t)(m0 + lrow) * lda + k0 + lcol);
        bf16x8 wv = *(const bf16x8*)(W + (size_t)(n0 + lrow) * ldw + k0 + lcol);
        __syncthreads();
        *(bf16x8*)&As[lrow][lcol] = av;
        *(bf16x8*)&Ws[lrow][lcol] = wv;
        __syncthreads();
        bf16x8 a0 = *(const bf16x8*)&As[wm + fr][fk];
        bf16x8 a1 = *(const bf16x8*)&As[wm + 16 + fr][fk];
        bf16x8 b0 = *(const bf16x8*)&Ws[wn + fr][fk];
        bf16x8 b1 = *(const bf16x8*)&Ws[wn + 16 + fr][fk];
        acc00 = __builtin_amdgcn_mfma_f32_16x16x32_bf16(a0, b0, acc00, 0, 0, 0);
        acc01 = __builtin_amdgcn_mfma_f32_16x16x32_bf16(a0, b1, acc01, 0, 0, 0);
        acc10 = __builtin_amdgcn_mfma_f32_16x16x32_bf16(a1, b0, acc10, 0, 0, 0);
        acc11 = __builtin_amdgcn_mfma_f32_16x16x32_bf16(a1, b1, acc11, 0, 0, 0);
    }
    const int cc = lane & 15, cr = (lane >> 4) * 4;
    float vb0 = bias ? bias[n0 + wn + cc] : 0.f;
    float vb1 = bias ? bias[n0 + wn + 16 + cc] : 0.f;
    floatx4 accs[2][2] = {{acc00, acc01}, {acc10, acc11}};
#pragma unroll
    for (int mt = 0; mt < 2; mt++)
#pragma unroll
        for (int nt = 0; nt < 2; nt++) {
            float vb = nt ? vb1 : vb0;
#pragma unroll
            for (int i = 0; i < 4; i++) {
                int gm = m0 + wm + mt * 16 + cr + i;
                int gn = n0 + wn + nt * 16 + cc;
                float v = accs[mt][nt][i] + vb;
                if (RELU) v = fmaxf(v, 0.f);
                if (OM == 1) ((bf16*)Cv)[(size_t)gm * ldc + gn] = (bf16)v;
                else         ((float*)Cv)[(size_t)gm * ldc + gn] = v;
            }
        }
}

// ---------------------------------------------------------------------------
// PNA front: pdps (1024 blks) + qgemm (2048 blks) + gh GEMM (384 blks) in ONE
// launch — all three depend only on out_bf / eaord (available at layer start).
// ---------------------------------------------------------------------------
__global__ __launch_bounds__(256) void k_pna_front(
    const bf16* __restrict__ out_bf, const bf16* __restrict__ Wnode_l,
    const float* __restrict__ bcombx_l, float* __restrict__ Pd, bf16* __restrict__ Ps,
    const bf16* __restrict__ eaord, const bf16* __restrict__ wcomb_l,
    bf16* __restrict__ Qord,
    const bf16* __restrict__ Whh, const float* __restrict__ bhh,
    float* __restrict__ gh)
{
    __shared__ char smem[46080];
    const int b = blockIdx.x;
    const int tid = threadIdx.x, wave = tid >> 6, lane = tid & 63;
    const int fr = lane & 15, fk = (lane >> 4) * 8;
    const int cc = lane & 15, cr = (lane >> 4) * 4;

    if (b < 1024 || b >= 3072) {
        // ---- 64x64 GEMM (pdps or gh), K=128 ----
        bf16 (*As)[40] = (bf16 (*)[40])smem;
        bf16 (*Ws)[40] = (bf16 (*)[40])(smem + 5120);
        const bool isGh = (b >= 3072);
        int m0, n0;
        const bf16* W;
        const float* bias;
        bool isPd = false;
        if (isGh) {
            int g = b - 3072;
            m0 = (g & 63) * 64; n0 = (g >> 6) * 64;
            W = Whh; bias = bhh;
        } else {
            m0 = (b & 63) * 64;
            int y = b >> 6;
            isPd = y < 8;
            n0 = (isPd ? y : y - 8) * 64;
            W = Wnode_l + (isPd ? 0 : (size_t)512 * 128);
            bias = bcombx_l;
        }
        const int wm = (wave & 1) * 32, wn = (wave >> 1) * 32;
        const int lrow = tid >> 2, lcol = (tid & 3) * 8;
        floatx4 acc00 = {0,0,0,0}, acc01 = {0,0,0,0}, acc10 = {0,0,0,0}, acc11 = {0,0,0,0};
        for (int k0 = 0; k0 < 128; k0 += 32) {
            bf16x8 av = *(const bf16x8*)(out_bf + (size_t)(m0 + lrow) * 128 + k0 + lcol);
            bf16x8 wv = *(const bf16x8*)(W + (size_t)(n0 + lrow) * 128 + k0 + lcol);
            __syncthreads();
            *(bf16x8*)&As[lrow][lcol] = av;
            *(bf16x8*)&Ws[lrow][lcol] = wv;
            __syncthreads();
            bf16x8 a0 = *(const bf16x8*)&As[wm + fr][fk];
            bf16x8 a1 = *(const bf16x8*)&As[wm + 16 + fr][fk];
            bf16x8 b0 = *(const bf16x8*)&Ws[wn + fr][fk];
            bf16x8 b1 = *(const bf16x8*)&Ws[wn + 16 + fr][fk];
            acc00 = __builtin_amdgcn_mfma_f32_16x16x32_bf16(a0, b0, acc00, 0, 0, 0);
            acc01 = __builtin_amdgcn_mfma_f32_16x16x32_bf16(a0, b1, acc01, 0, 0, 0);
            acc10 = __builtin_amdgcn_mfma_f32_16x16x32_bf16(a1, b0, acc10, 0, 0, 0);
            acc11 = __builtin_amdgcn_mfma_f32_16x16x32_bf16(a1, b1, acc11, 0, 0, 0);
        }
        float vb0 = (isGh || isPd) ? bias[n0 + wn + cc] : 0.f;
        float vb1 = (isGh || isPd) ? bias[n0 + wn + 16 + cc] : 0.f;
        floatx4 accs[2][2] = {{acc00, acc01}, {acc10, acc11}};
#pragma unroll
        for (int mt = 0; mt < 2; mt++)
#pragma unroll
            for (int nt = 0; nt < 2; nt++) {
                float vb = nt ? vb1 : vb0;
#pragma unroll
                for (int i = 0; i < 4; i++) {
                    int gm = m0 + wm + mt * 16 + cr + i;
                    int gn = n0 + wn + nt * 16 + cc;
                    float v = accs[mt][nt][i] + vb;
                    if (isGh)      gh[(size_t)gm * 384 + gn] = v;
                    else if (isPd) Pd[(size_t)gm * 512 + gn] = v;
                    else           Ps[(size_t)gm * 512 + gn] = (bf16)v;
                }
            }
    } else {
        // ---- qgemm: Q_ord[E,512] = eaord[E,64] @ wcomb[512,64]^T ----
        bf16 (*As)[72] = (bf16 (*)[72])smem;               // 64x72x2 = 9216
        bf16 (*Ws)[72] = (bf16 (*)[72])(smem + 9216);      // 256x72x2 = 36864
        int q = b - 1024;
        const int e0 = (q & 1023) * 64, n0g = (q >> 10) * 256;
#pragma unroll
        for (int v = 0; v < 2; v++) {
            int lin = v * 2048 + tid * 8;
            int r = lin >> 6, c = lin & 63;
            *(bf16x8*)&As[r][c] = *(const bf16x8*)(eaord + (size_t)(e0 + r) * 64 + c);
        }
#pragma unroll
        for (int v = 0; v < 8; v++) {
            int lin = v * 2048 + tid * 8;
            int r = lin >> 6, c = lin & 63;
            *(bf16x8*)&Ws[r][c] = *(const bf16x8*)(wcomb_l + (size_t)(n0g + r) * 64 + c);
        }
        __syncthreads();

        floatx4 acc[4][4];
#pragma unroll
        for (int mt = 0; mt < 4; mt++)
#pragma unroll
            for (int nt = 0; nt < 4; nt++) acc[mt][nt] = (floatx4){0,0,0,0};

#pragma unroll
        for (int kk = 0; kk < 64; kk += 32) {
            bf16x8 af[4], bv[4];
#pragma unroll
            for (int mt = 0; mt < 4; mt++) af[mt] = *(const bf16x8*)&As[mt * 16 + fr][kk + fk];
#pragma unroll
            for (int nt = 0; nt < 4; nt++) bv[nt] = *(const bf16x8*)&Ws[wave * 64 + nt * 16 + fr][kk + fk];
#pragma unroll
            for (int mt = 0; mt < 4; mt++)
#pragma unroll
                for (int nt = 0; nt < 4; nt++)
                    acc[mt][nt] = __builtin_amdgcn_mfma_f32_16x16x32_bf16(af[mt], bv[nt], acc[mt][nt], 0, 0, 0);
        }
#pragma unroll
        for (int mt = 0; mt < 4; mt++)
#pragma unroll
            for (int nt = 0; nt < 4; nt++)
#pragma unroll
                for (int i = 0; i < 4; i++) {
                    int row = mt * 16 + cr + i;
                    int col = n0g + wave * 64 + nt * 16 + cc;
                    Qord[(size_t)(e0 + row) * 512 + col] = (bf16)acc[mt][nt][i];
                }
    }
}

// ---------------------------------------------------------------------------
// gi GEMM: gi = m_bf @ Wih^T + bih. grid (64,6), ldc 384, f32 out.
// (R10's single-wave fused gigru regressed: 1 wave/CU occupancy + scattered
// per-lane B loads. LDS-staged 4-wave GEMM is the validated form.)
// ---------------------------------------------------------------------------
__global__ __launch_bounds__(256) void k_gi(
    const bf16* __restrict__ m_bf, const bf16* __restrict__ Wih,
    const float* __restrict__ bih, float* __restrict__ gi)
{
    __shared__ bf16 As[64][40];
    __shared__ bf16 Ws[64][40];
    const int m0 = blockIdx.x * 64, n0 = blockIdx.y * 64;
    const int tid = threadIdx.x, wave = tid >> 6, lane = tid & 63;
    const int wm = (wave & 1) * 32, wn = (wave >> 1) * 32;
    const int lrow = tid >> 2, lcol = (tid & 3) * 8;
    const int fr = lane & 15, fk = (lane >> 4) * 8;
    floatx4 acc00 = {0,0,0,0}, acc01 = {0,0,0,0}, acc10 = {0,0,0,0}, acc11 = {0,0,0,0};

    for (int k0 = 0; k0 < 128; k0 += 32) {
        bf16x8 av = *(const bf16x8*)(m_bf + (size_t)(m0 + lrow) * 128 + k0 + lcol);
        bf16x8 wv = *(const bf16x8*)(Wih + (size_t)(n0 + lrow) * 128 + k0 + lcol);
        __syncthreads();
        *(bf16x8*)&As[lrow][lcol] = av;
        *(bf16x8*)&Ws[lrow][lcol] = wv;
        __syncthreads();
        bf16x8 a0 = *(const bf16x8*)&As[wm + fr][fk];
        bf16x8 a1 = *(const bf16x8*)&As[wm + 16 + fr][fk];
        bf16x8 b0 = *(const bf16x8*)&Ws[wn + fr][fk];
        bf16x8 b1 = *(const bf16x8*)&Ws[wn + 16 + fr][fk];
        acc00 = __builtin_amdgcn_mfma_f32_16x16x32_bf16(a0, b0, acc00, 0, 0, 0);
        acc01 = __builtin_amdgcn_mfma_f32_16x16x32_bf16(a0, b1, acc01, 0, 0, 0);
        acc10 = __builtin_amdgcn_mfma_f32_16x16x32_bf16(a1, b0, acc10, 0, 0, 0);
        acc11 = __builtin_amdgcn_mfma_f32_16x16x32_bf16(a1, b1, acc11, 0, 0, 0);
    }
    const int cc = lane & 15, cr = (lane >> 4) * 4;
    float vb0 = bih[n0 + wn + cc];
    float vb1 = bih[n0 + wn + 16 + cc];
    floatx4 accs[2][2] = {{acc00, acc01}, {acc10, acc11}};
#pragma unroll
    for (int mt = 0; mt < 2; mt++)
#pragma unroll
        for (int nt = 0; nt < 2; nt++) {
            float vb = nt ? vb1 : vb0;
#pragma unroll
            for (int i = 0; i < 4; i++) {
                int gm = m0 + wm + mt * 16 + cr + i;
                int gn = n0 + wn + nt * 16 + cc;
                gi[(size_t)gm * 384 + gn] = accs[mt][nt][i] + vb;
            }
        }
}

// ---------------------------------------------------------------------------
// Fused edge update — R8-validated: per-k-step A gather + LDS weight staging
// + T14 register prefetch (cross-stage pipelined). LDS 53248 B → 3 blocks/CU.
// (R9's direct-operand variant regressed: lost coalescing. Staging is
// load-bearing here.)
// ---------------------------------------------------------------------------
__global__ __launch_bounds__(256) void k_edge(
    const bf16* __restrict__ SAB,
    const bf16* __restrict__ em2W, const float* __restrict__ em2b,
    const bf16* __restrict__ eu1W, const float* __restrict__ eu1b,
    const bf16* __restrict__ eu2W, const float* __restrict__ eu2b,
    const int* __restrict__ src, const int* __restrict__ dst,
    const int* __restrict__ pos,
    bf16* __restrict__ eaord, float* __restrict__ ea_out_f)
{
    __shared__ char smem[53248];
    bf16 (*Ws)[40]   = (bf16 (*)[40])smem;                 // 128x40 = 10240 B
    bf16 (*med)[200] = (bf16 (*)[200])(smem + 10240);      // 64x200 = 25600 B
    bf16 (*As)[40]   = (bf16 (*)[40])(smem + 35840);       // 64x40 = 5120 B (stage 1; aliases t2s)
    bf16 (*t2s)[136] = (bf16 (*)[136])(smem + 35840);      // 64x136 = 17408 B (stages 2-3)

    const int e0 = blockIdx.x * 64;
    const int tid = threadIdx.x, wave = tid >> 6, lane = tid & 63;
    const int lrow = tid >> 2, lcol = (tid & 3) * 8;
    const int fr = lane & 15, fk = (lane >> 4) * 8;
    const int cc = lane & 15, cr = (lane >> 4) * 4;
    const int wr = tid & 127, wc = (tid >> 7) * 16;        // stage 1/2 W loader
    const int wr3 = tid & 63, wc3 = (tid >> 6) * 8;        // stage 3 W loader
    const int sI = src[e0 + lrow], dI = dst[e0 + lrow];
    const floatx4 z4 = {0.f, 0.f, 0.f, 0.f};

    // early gather: ea append tile (consumed at end of stage 1)
    const int ac0 = (tid & 3) * 16;
    const int apr = pos[e0 + lrow];
    bf16x8 ea0 = *(const bf16x8*)(eaord + (size_t)apr * 64 + ac0);
    bf16x8 ea1 = *(const bf16x8*)(eaord + (size_t)apr * 64 + ac0 + 8);

    // ---------- stage 1: m_ed = relu(A @ em2W^T + em2b)  [64x128, K=256] ----------
    const int wm1 = (wave & 1) * 32, wn1 = (wave >> 1) * 64;
    floatx4 acc1[2][4];
#pragma unroll
    for (int mt = 0; mt < 2; mt++)
#pragma unroll
        for (int nt = 0; nt < 4; nt++) acc1[mt][nt] = z4;

    // prologue prefetch (k0 = 0)
    bf16x8 sv = *(const bf16x8*)(SAB + (size_t)sI * 512 + lcol);
    bf16x8 dv = *(const bf16x8*)(SAB + (size_t)dI * 512 + 256 + lcol);
    bf16x8 w0 = *(const bf16x8*)(em2W + (size_t)wr * 256 + wc);
    bf16x8 w1 = *(const bf16x8*)(em2W + (size_t)wr * 256 + wc + 8);

    for (int k0 = 0; k0 < 256; k0 += 32) {
        __syncthreads();
        bf16 a8[8];
#pragma unroll
        for (int j = 0; j < 8; j++)
            a8[j] = (bf16)fmaxf((float)sv[j] + (float)dv[j], 0.f);
        *(bf16x8*)&As[lrow][lcol] = *(bf16x8*)a8;
        *(bf16x8*)&Ws[wr][wc]     = w0;
        *(bf16x8*)&Ws[wr][wc + 8] = w1;
        int kn = k0 + 32;
        if (kn < 256) {
            sv = *(const bf16x8*)(SAB + (size_t)sI * 512 + kn + lcol);
            dv = *(const bf16x8*)(SAB + (size_t)dI * 512 + 256 + kn + lcol);
            w0 = *(const bf16x8*)(em2W + (size_t)wr * 256 + kn + wc);
            w1 = *(const bf16x8*)(em2W + (size_t)wr * 256 + kn + wc + 8);
        } else {
            // cross-stage prefetch: stage-2's first weight slice
            w0 = *(const bf16x8*)(eu1W + (size_t)wr * 192 + wc);
            w1 = *(const bf16x8*)(eu1W + (size_t)wr * 192 + wc + 8);
        }
        __syncthreads();
        bf16x8 af[2], bv[4];
        af[0] = *(const bf16x8*)&As[wm1 + fr][fk];
        af[1] = *(const bf16x8*)&As[wm1 + 16 + fr][fk];
#pragma unroll
        for (int nt = 0; nt < 4; nt++) bv[nt] = *(const bf16x8*)&Ws[wn1 + nt * 16 + fr][fk];
#pragma unroll
        for (int mt = 0; mt < 2; mt++)
#pragma unroll
            for (int nt = 0; nt < 4; nt++)
                acc1[mt][nt] = __builtin_amdgcn_mfma_f32_16x16x32_bf16(af[mt], bv[nt], acc1[mt][nt], 0, 0, 0);
    }
    // med region is disjoint from As/Ws — no barrier needed before these writes
#pragma unroll
    for (int mt = 0; mt < 2; mt++)
#pragma unroll
        for (int nt = 0; nt < 4; nt++)
#pragma unroll
            for (int i = 0; i < 4; i++) {
                int row = wm1 + mt * 16 + cr + i;
                int col = wn1 + nt * 16 + cc;
                med[row][col] = (bf16)fmaxf(acc1[mt][nt][i] + em2b[col], 0.f);
            }
    // append ea tile from the early-gathered registers
    *(bf16x8*)&med[lrow][128 + ac0]     = ea0;
    *(bf16x8*)&med[lrow][128 + ac0 + 8] = ea1;
    // med-ready sync provided by stage-2's first in-loop barrier

    // ---------- stage 2: t2 = relu([m_ed|ea] @ eu1W^T + eu1b)  [64x128, K=192] ----------
    floatx4 acc2[2][4];
#pragma unroll
    for (int mt = 0; mt < 2; mt++)
#pragma unroll
        for (int nt = 0; nt < 4; nt++) acc2[mt][nt] = z4;

    for (int k0 = 0; k0 < 192; k0 += 32) {
        __syncthreads();
        *(bf16x8*)&Ws[wr][wc]     = w0;
        *(bf16x8*)&Ws[wr][wc + 8] = w1;
        int kn = k0 + 32;
        if (kn < 192) {
            w0 = *(const bf16x8*)(eu1W + (size_t)wr * 192 + kn + wc);
            w1 = *(const bf16x8*)(eu1W + (size_t)wr * 192 + kn + wc + 8);
        } else {
            // cross-stage prefetch: stage-3's first weight slice
            w0 = *(const bf16x8*)(eu2W + (size_t)wr3 * 128 + wc3);
        }
        __syncthreads();
        bf16x8 af[2], bv[4];
        af[0] = *(const bf16x8*)&med[wm1 + fr][k0 + fk];
        af[1] = *(const bf16x8*)&med[wm1 + 16 + fr][k0 + fk];
#pragma unroll
        for (int nt = 0; nt < 4; nt++) bv[nt] = *(const bf16x8*)&Ws[wn1 + nt * 16 + fr][fk];
#pragma unroll
        for (int mt = 0; mt < 2; mt++)
#pragma unroll
            for (int nt = 0; nt < 4; nt++)
                acc2[mt][nt] = __builtin_amdgcn_mfma_f32_16x16x32_bf16(af[mt], bv[nt], acc2[mt][nt], 0, 0, 0);
    }
    // t2s aliases As (dead since end of stage 1); disjoint from med and Ws
#pragma unroll
    for (int mt = 0; mt < 2; mt++)
#pragma unroll
        for (int nt = 0; nt < 4; nt++)
#pragma unroll
            for (int i = 0; i < 4; i++) {
                int row = wm1 + mt * 16 + cr + i;
                int col = wn1 + nt * 16 + cc;
                t2s[row][col] = (bf16)fmaxf(acc2[mt][nt][i] + eu1b[col], 0.f);
            }
    // t2s-ready sync provided by stage-3's first in-loop barrier

    // ---------- stage 3: ea' = t2 @ eu2W^T + eu2b  [64x64, K=128] ----------
    const int wm3 = (wave & 1) * 32, wn3 = (wave >> 1) * 32;
    floatx4 acc3[2][2];
#pragma unroll
    for (int mt = 0; mt < 2; mt++)
#pragma unroll
        for (int nt = 0; nt < 2; nt++) acc3[mt][nt] = z4;

    for (int k0 = 0; k0 < 128; k0 += 32) {
        __syncthreads();
        *(bf16x8*)&Ws[wr3][wc3] = w0;
        int kn = k0 + 32;
        if (kn < 128)
            w0 = *(const bf16x8*)(eu2W + (size_t)wr3 * 128 + kn + wc3);
        __syncthreads();
        bf16x8 af[2], bv[2];
        af[0] = *(const bf16x8*)&t2s[wm3 + fr][k0 + fk];
        af[1] = *(const bf16x8*)&t2s[wm3 + 16 + fr][k0 + fk];
#pragma unroll
        for (int nt = 0; nt < 2; nt++) bv[nt] = *(const bf16x8*)&Ws[wn3 + nt * 16 + fr][fk];
#pragma unroll
        for (int mt = 0; mt < 2; mt++)
#pragma unroll
            for (int nt = 0; nt < 2; nt++)
                acc3[mt][nt] = __builtin_amdgcn_mfma_f32_16x16x32_bf16(af[mt], bv[nt], acc3[mt][nt], 0, 0, 0);
    }
#pragma unroll
    for (int mt = 0; mt < 2; mt++)
#pragma unroll
        for (int nt = 0; nt < 2; nt++)
#pragma unroll
            for (int i = 0; i < 4; i++) {
                int row = wm3 + mt * 16 + cr + i;
                int col = wn3 + nt * 16 + cc;
                float v = acc3[mt][nt][i] + eu2b[col];
                int e = e0 + row;
                eaord[(size_t)pos[e] * 64 + col] = (bf16)v;
                if (ea_out_f) ea_out_f[(size_t)e * 64 + col] = v;  // final layer only
            }
}

// ---------------------------------------------------------------------------
// Post-MLP per-tower MFMA GEMM — consumes bf16 agg buffers
// ---------------------------------------------------------------------------
__global__ __launch_bounds__(256) void k_postg(
    const bf16* __restrict__ xin, const bf16* __restrict__ aggX,
    const bf16* __restrict__ aggS, const bf16* __restrict__ aggM,
    const bf16* __restrict__ qWbf, const float* __restrict__ qb,
    bf16* __restrict__ ybf)
{
    __shared__ bf16 As[64][40];
    __shared__ bf16 Ws[32][40];
    const int n0 = blockIdx.x * 64, t = blockIdx.y;
    const int tid = threadIdx.x, wave = tid >> 6, lane = tid & 63;
    const int lrow = tid >> 2, lcol = (tid & 3) * 8;
    const int fr = lane & 15, fk = (lane >> 4) * 8;
    floatx4 acc0 = {0,0,0,0}, acc1 = {0,0,0,0};

    for (int k0 = 0; k0 < 512; k0 += 32) {
        int n = n0 + lrow;
        int c0 = k0 + lcol;
        const bf16* srcp;
        if (c0 < 128)      srcp = xin  + (size_t)n * 128 + c0;
        else if (c0 < 256) srcp = aggX + (size_t)n * 512 + t * 128 + (c0 - 128);
        else if (c0 < 384) srcp = aggS + (size_t)n * 512 + t * 128 + (c0 - 256);
        else               srcp = aggM + (size_t)n * 512 + t * 128 + (c0 - 384);
        bf16x8 a8 = *(const bf16x8*)srcp;
        bf16 w8[8];
        if (tid < 128) {
            int wr = tid >> 2, wc = (tid & 3) * 8;
            *(bf16x8*)w8 = *(const bf16x8*)(qWbf + (size_t)(t * 32 + wr) * 512 + k0 + wc);
        }
        __syncthreads();
        *(bf16x8*)&As[lrow][lcol] = a8;
        if (tid < 128) {
            int wr = tid >> 2, wc = (tid & 3) * 8;
            *(bf16x8*)&Ws[wr][wc] = *(bf16x8*)w8;
        }
        __syncthreads();
        bf16x8 a  = *(const bf16x8*)&As[wave * 16 + fr][fk];
        bf16x8 b0 = *(const bf16x8*)&Ws[fr][fk];
        bf16x8 b1 = *(const bf16x8*)&Ws[16 + fr][fk];
        acc0 = __builtin_amdgcn_mfma_f32_16x16x32_bf16(a, b0, acc0, 0, 0, 0);
        acc1 = __builtin_amdgcn_mfma_f32_16x16x32_bf16(a, b1, acc1, 0, 0, 0);
    }
    const int cc = lane & 15, cr = (lane >> 4) * 4;
#pragma unroll
    for (int i = 0; i < 4; i++) {
        int gn = n0 + wave * 16 + cr + i;
        ybf[(size_t)gn * 128 + t * 32 + cc]      = (bf16)(acc0[i] + qb[t * 32 + cc]);
        ybf[(size_t)gn * 128 + t * 32 + 16 + cc] = (bf16)(acc1[i] + qb[t * 32 + 16 + cc]);
    }
}

// ----------------------- CSR scan / fill ------------------------------------
__global__ __launch_bounds__(1024) void k_scan(
    const int* __restrict__ counts, int* __restrict__ offs, int* __restrict__ cursor)
{
    __shared__ int ls[1024];
    int tid = threadIdx.x, base = tid * 4;
    int c0 = counts[base], c1 = counts[base + 1], c2 = counts[base + 2], c3 = counts[base + 3];
    ls[tid] = c0 + c1 + c2 + c3;
    __syncthreads();
    for (int d = 1; d < 1024; d <<= 1) {
        int v = (tid >= d) ? ls[tid - d] : 0;
        __syncthreads();
        ls[tid] += v;
        __syncthreads();
    }
    int r = tid ? ls[tid - 1] : 0;
    offs[base] = r;     cursor[base] = r;     r += c0;
    offs[base + 1] = r; cursor[base + 1] = r; r += c1;
    offs[base + 2] = r; cursor[base + 2] = r; r += c2;
    offs[base + 3] = r; cursor[base + 3] = r; r += c3;
    if (tid == 1023) offs[4096] = r;
}

__global__ void k_fill(const int* __restrict__ dst, const int* __restrict__ srcW,
                       int* __restrict__ cursor, int* __restrict__ pos,
                       int* __restrict__ srcord)
{
    int e = blockIdx.x * 256 + threadIdx.x;
    int p = atomicAdd(&cursor[dst[e]], 1);
    pos[e] = p;
    srcord[p] = srcW[e];
}

// ---------------------------------------------------------------------------
// Single-pass aggregation. Pd f32 (own row, sequential); Ps bf16 L2-resident.
// ---------------------------------------------------------------------------
__global__ __launch_bounds__(128) void k_agg(
    const float* __restrict__ Pd, const bf16* __restrict__ Ps,
    const bf16* __restrict__ Qord,
    const int* __restrict__ srcord, const int* __restrict__ offs,
    bf16* __restrict__ aggX, bf16* __restrict__ aggS, bf16* __restrict__ aggM)
{
    int n = blockIdx.x, tid = threadIdx.x;
    int c = tid * 4;
    float4 pd = *(const float4*)(Pd + (size_t)n * 512 + c);
    float s0 = 0, s1 = 0, s2 = 0, s3 = 0;
    float q0 = 0, q1 = 0, q2 = 0, q3 = 0;
    float x0 = -3e38f, x1 = -3e38f, x2 = -3e38f, x3 = -3e38f;
    int beg = offs[n], end = offs[n + 1];
    for (int i = beg; i < end; i++) {
        int sn = srcord[i];
        bf16x4 psv = *(const bf16x4*)(Ps + (size_t)sn * 512 + c);
        bf16x4 qv  = *(const bf16x4*)(Qord + (size_t)i * 512 + c);
        float m0 = pd.x + (float)psv[0] + (float)qv[0];
        float m1 = pd.y + (float)psv[1] + (float)qv[1];
        float m2 = pd.z + (float)psv[2] + (float)qv[2];
        float m3 = pd.w + (float)psv[3] + (float)qv[3];
        s0 += m0; s1 += m1; s2 += m2; s3 += m3;
        q0 += m0 * m0; q1 += m1 * m1; q2 += m2 * m2; q3 += m3 * m3;
        x0 = fmaxf(x0, m0); x1 = fmaxf(x1, m1); x2 = fmaxf(x2, m2); x3 = fmaxf(x3, m3);
    }
    int cnt = end - beg;
    float inv = 1.f / fmaxf((float)cnt, 1.f);
    float me0 = s0 * inv, me1 = s1 * inv, me2 = s2 * inv, me3 = s3 * inv;
    float v0 = fmaxf(q0 * inv - me0 * me0, 0.f);
    float v1 = fmaxf(q1 * inv - me1 * me1, 0.f);
    float v2 = fmaxf(q2 * inv - me2 * me2, 0.f);
    float v3 = fmaxf(q3 * inv - me3 * me3, 0.f);
    size_t o = (size_t)n * 512 + c;
    bf16x4 mx, st, me;
    mx[0] = (bf16)(cnt > 0 ? x0 : 0.f); mx[1] = (bf16)(cnt > 0 ? x1 : 0.f);
    mx[2] = (bf16)(cnt > 0 ? x2 : 0.f); mx[3] = (bf16)(cnt > 0 ? x3 : 0.f);
    st[0] = (bf16)sqrtf(v0 + 1e-5f); st[1] = (bf16)sqrtf(v1 + 1e-5f);
    st[2] = (bf16)sqrtf(v2 + 1e-5f); st[3] = (bf16)sqrtf(v3 + 1e-5f);
    me[0] = (bf16)me0; me[1] = (bf16)me1; me[2] = (bf16)me2; me[3] = (bf16)me3;
    *(bf16x4*)(aggX + o) = mx;
    *(bf16x4*)(aggS + o) = st;
    *(bf16x4*)(aggM + o) = me;
}

// --------------------------- GRU elementwise --------------------------------
__global__ void k_gru(const float* __restrict__ gi, const float* __restrict__ gh,
                      float* __restrict__ hst, bf16* __restrict__ ob,
                      float* __restrict__ fo)
{
    int i = blockIdx.x * 256 + threadIdx.x;
    int k = i & 127;
    size_t b = (size_t)(i >> 7) * 384;
    float ir = gi[b + k],       hr = gh[b + k];
    float iz = gi[b + 128 + k], hz = gh[b + 128 + k];
    float ic = gi[b + 256 + k], hc = gh[b + 256 + k];
    float r = 1.f / (1.f + __expf(-(ir + hr)));
    float z = 1.f / (1.f + __expf(-(iz + hz)));
    float c = tanhf(ic + r * hc);
    float h = hst[i];
    float hn = (1.f - z) * c + z * h;
    hst[i] = hn;
    ob[i] = (bf16)hn;
    if (fo) { fo[i] = hn; fo[4718592 + i] = hn; }
}

__global__ void k_sentinel(float* __restrict__ o, float v)
{
    int i = blockIdx.x * 256 + threadIdx.x;
    o[i] = v;
}

// ===========================================================================
extern "C" void kernel_launch(void* const* d_in, const int* in_sizes, int n_in,
                              void* d_out, int out_size, void* d_ws, size_t ws_size,
                              hipStream_t stream)
{
    static const int exp_sizes[23] = {
        524288, 4194304, 131072, 24576, 384, 589824, 1536, 196608, 384,
        49152, 384, 49152, 49152, 384, 384, 65536, 256, 32768, 128,
        24576, 128, 8192, 64 };
    if (n_in != 23) { k_sentinel<<<2048, 256, 0, stream>>>((float*)d_out, 200.f); return; }
    for (int i = 0; i < 23; i++)
        if (in_sizes[i] != exp_sizes[i]) {
            k_sentinel<<<2048, 256, 0, stream>>>((float*)d_out, 60.f + 4.f * i);
            return;
        }
    if (out_size != 5242880) { k_sentinel<<<2048, 256, 0, stream>>>((float*)d_out, 52.f); return; }

    const int* eidx = (const int*)d_in[2];

    char* w = (char*)d_ws;
    size_t off = 0;
    auto alloc = [&](size_t bytes) -> char* {
        char* p = w + off;
        off = (off + bytes + 255) & ~(size_t)255;
        return p;
    };
    int*   dflag   = (int*)  alloc(256);
    int*   iflag   = (int*)  alloc(256);
    int*   srcW    = (int*)  alloc((size_t)EE * 4);
    int*   dstW    = (int*)  alloc((size_t)EE * 4);
    int*   pos     = (int*)  alloc((size_t)EE * 4);
    int*   srcord  = (int*)  alloc((size_t)EE * 4);
    float* out_f32 = (float*)alloc((size_t)NN * HH * 4);
    bf16*  out_bf  = (bf16*) alloc((size_t)NN * HH * 2);
    bf16*  m_bf    = (bf16*) alloc((size_t)NN * HH * 2);
    bf16*  ybf     = (bf16*) alloc((size_t)NN * HH * 2);
    bf16*  eaord   = (bf16*) alloc((size_t)EE * EDD * 2);
    bf16*  wcombAll= (bf16*) alloc((size_t)3 * THD * EDD * 2);
    float* bcombAll= (float*)alloc((size_t)3 * 1024 * 4);
    int*   counts  = (int*)  alloc((size_t)NN * 4);
    int*   offs    = (int*)  alloc((size_t)(NN + 1) * 4);
    int*   cursor  = (int*)  alloc((size_t)NN * 4);
    float* Pd      = (float*)alloc((size_t)NN * THD * 4);   // [4096,512] f32
    bf16*  Ps      = (bf16*) alloc((size_t)NN * THD * 2);   // [4096,512] bf16 (L2-resident)
    bf16*  aggX    = (bf16*) alloc((size_t)NN * THD * 2);
    bf16*  aggS    = (bf16*) alloc((size_t)NN * THD * 2);
    bf16*  aggM    = (bf16*) alloc((size_t)NN * THD * 2);
    float* giB     = (float*)alloc((size_t)NN * 384 * 4);
    float* ghB     = (float*)alloc((size_t)NN * 384 * 4);
    float* encWc  = (float*)alloc((size_t)24576 * 4);
    float* encbc  = (float*)alloc((size_t)384 * 4);
    float* preWc  = (float*)alloc((size_t)589824 * 4);
    float* prebc  = (float*)alloc((size_t)1536 * 4);
    float* postbc = (float*)alloc((size_t)384 * 4);
    float* linbc  = (float*)alloc((size_t)384 * 4);
    float* bihc   = (float*)alloc((size_t)384 * 4);
    float* bhhc   = (float*)alloc((size_t)384 * 4);
    float* em1bc  = (float*)alloc((size_t)256 * 4);
    float* em1ext = (float*)alloc((size_t)512 * 4);
    float* em2bc  = (float*)alloc((size_t)128 * 4);
    float* eu1bc  = (float*)alloc((size_t)128 * 4);
    float* eu2bc  = (float*)alloc((size_t)64 * 4);
    bf16* preWbf = (bf16*)alloc((size_t)589824 * 2);
    bf16* WnodeBf= (bf16*)alloc((size_t)3 * 131072 * 2);
    bf16* postWbf= (bf16*)alloc((size_t)196608 * 2);
    bf16* linWbf = (bf16*)alloc((size_t)49152 * 2);
    bf16* WihBf  = (bf16*)alloc((size_t)49152 * 2);
    bf16* WhhBf  = (bf16*)alloc((size_t)49152 * 2);
    bf16* em1Wbf = (bf16*)alloc((size_t)65536 * 2);
    bf16* Wem1Bf = (bf16*)alloc((size_t)65536 * 2);
    bf16* em2Wbf = (bf16*)alloc((size_t)32768 * 2);
    bf16* eu1Wbf = (bf16*)alloc((size_t)24576 * 2);
    bf16* eu2Wbf = (bf16*)alloc((size_t)8192 * 2);
    // phase-shared region: Q_ord (PNA) / SAB (edge, bf16)
    char* region = alloc((size_t)EE * 512 * 2);     // 67.1 MB
    bf16*  Qord = (bf16*) (region);
    bf16*  SAB  = (bf16*) (region);                 // [N,512] bf16 = 4.2 MB

    if (ws_size < off) { k_sentinel<<<2048, 256, 0, stream>>>((float*)d_out, 44.f); return; }

    // ---- setup: detect+zero / extidx+count / scan / fill ----
    k_det0<<<18, 256, 0, stream>>>(d_in[1], eidx, dflag, iflag, counts);
    k_extcnt<<<EE / 256, 256, 0, stream>>>(eidx, srcW, dstW, iflag, counts);
    k_scan<<<1, 1024, 0, stream>>>(counts, offs, cursor);
    k_fill<<<EE / 256, 256, 0, stream>>>(dstW, srcW, cursor, pos, srcord);

    // ---- ONE mega-canon launch ----
    {
        JobTab tab;
        int bi = 0, ji = 0;
        auto add = [&](const void* s, void* d1, void* d2, int n, int mode) {
            tab.j[ji] = { s, d1, d2, n, mode, bi };
            bi += (n + 255) / 256;
            ji++;
        };
        add(d_in[0],  out_f32, out_bf, 524288, 2);
        add(d_in[1],  eaord,   nullptr, 4194304, 3);
        add(d_in[5],  preWc,   preWbf, 589824, 2);
        add(d_in[3],  encWc,   nullptr, 24576, 0);
        add(d_in[4],  encbc,   nullptr, 384, 0);
        add(d_in[6],  prebc,   nullptr, 1536, 0);
        add(d_in[8],  postbc,  nullptr, 384, 0);
        add(d_in[10], linbc,   nullptr, 384, 0);
        add(d_in[13], bihc,    nullptr, 384, 0);
        add(d_in[14], bhhc,    nullptr, 384, 0);
        add(d_in[16], em1bc,   nullptr, 256, 0);
        add(d_in[18], em2bc,   nullptr, 128, 0);
        add(d_in[20], eu1bc,   nullptr, 128, 0);
        add(d_in[22], eu2bc,   nullptr, 64, 0);
        add(d_in[7],  postWbf, nullptr, 196608, 1);
        add(d_in[9],  linWbf,  nullptr, 49152, 1);
        add(d_in[11], WihBf,   nullptr, 49152, 1);
        add(d_in[12], WhhBf,   nullptr, 49152, 1);
        add(d_in[15], em1Wbf,  nullptr, 65536, 1);
        add(d_in[17], em2Wbf,  nullptr, 32768, 1);
        add(d_in[19], eu1Wbf,  nullptr, 24576, 1);
        add(d_in[21], eu2Wbf,  nullptr, 8192, 1);
        k_canon_all<<<bi, 256, 0, stream>>>(tab, dflag, pos);
    }
    // ---- fused repacks + all-layer wcomb ----
    k_setup2<<<2178, 256, 0, stream>>>(preWbf, em1Wbf, em1bc, WnodeBf, Wem1Bf, em1ext,
                                       preWc, encWc, encbc, prebc, wcombAll, bcombAll);

    auto GEMM = [&](const bf16* A, int lda, const bf16* Wm, int ldw, const float* bias,
                    void* C, int ldc, int M, int Nout, int K, bool relu, int om) {
        dim3 grid(M / 64, Nout / 64);
        if (relu) {
            if (om) k_mgemm<true, 1><<<grid, 256, 0, stream>>>(A, lda, Wm, ldw, bias, C, ldc, K);
            else    k_mgemm<true, 0><<<grid, 256, 0, stream>>>(A, lda, Wm, ldw, bias, C, ldc, K);
        } else {
            if (om) k_mgemm<false, 1><<<grid, 256, 0, stream>>>(A, lda, Wm, ldw, bias, C, ldc, K);
            else    k_mgemm<false, 0><<<grid, 256, 0, stream>>>(A, lda, Wm, ldw, bias, C, ldc, K);
        }
    };

    for (int l = 0; l < 3; l++) {
        const bf16*  Wnode_l  = WnodeBf + (size_t)l * 131072;
        const bf16*  postW_l  = postWbf + (size_t)l * 65536;
        const float* postb_l  = postbc + (size_t)l * 128;
        const bf16*  linW_l   = linWbf + (size_t)l * 16384;
        const float* linb_l   = linbc  + (size_t)l * 128;
        const bf16*  wcomb_l  = wcombAll + (size_t)l * 32768;
        const float* bcombx_l = bcombAll + (size_t)l * 1024;
        const bool last = (l == 2);

        // ---- PNA front: pdps + qgemm + gh in one launch ----
        k_pna_front<<<3456, 256, 0, stream>>>(out_bf, Wnode_l, bcombx_l, Pd, Ps,
                                              eaord, wcomb_l, Qord, WhhBf, bhhc, ghB);
        k_agg<<<NN, 128, 0, stream>>>(Pd, Ps, Qord, srcord, offs, aggX, aggS, aggM);
        k_postg<<<dim3(NN / 64, 4), 256, 0, stream>>>(out_bf, aggX, aggS, aggM,
                                                      postW_l, postb_l, ybf);
        GEMM(ybf, HH, linW_l, HH, linb_l, m_bf, HH, NN, HH, HH, true, 1);
        // ---- GRU: gi then elementwise (gh precomputed in pna_front) ----
        k_gi<<<dim3(64, 6), 256, 0, stream>>>(m_bf, WihBf, bihc, giB);
        k_gru<<<NN * HH / 256, 256, 0, stream>>>(giB, ghB, out_f32, out_bf,
                                                 last ? (float*)d_out : (float*)nullptr);
        // ---- edge update (merged SAB + fused chain; SAB bf16) ----
        GEMM(out_bf, HH, Wem1Bf, 128, em1ext, SAB, 512, NN, 512, HH, false, 1);
        k_edge<<<EE / 64, 256, 0, stream>>>(SAB, em2Wbf, em2bc, eu1Wbf, eu1bc,
                                            eu2Wbf, eu2bc, srcW, dstW, pos,
                                            eaord, last ? (float*)d_out + 524288 : (float*)nullptr);
    }
}